// Round 8
// baseline (2534.017 us; speedup 1.0000x reference)
//
#include <hip/hip_runtime.h>
#include <hip/hip_bf16.h>
#include <math.h>

// ============================================================================
// GMMLoss2_pca v8: fused blocked CholQR-256 small-matrix kernel (qrf_k builds
// Rinv 256x256 in one launch; S-update = single GEMM), LDS pitch 129
// (conflict-free chol), KS=8 on the Cn build. Pipeline otherwise = v7.
// ============================================================================

#define B_N 8192
#define D_N 1024
#define K_N 128
#define M_N 256
#define NLAB 10

__device__ __forceinline__ float hashf(unsigned x) {
  x ^= x >> 16; x *= 0x7feb352du; x ^= x >> 15; x *= 0x846ca68bu; x ^= x >> 16;
  return (float)(x >> 8) * (1.0f / 16777216.0f) - 0.5f;
}

// ---------------------------------------------------------------------------
// Tiled f32 GEMM (validated v4-v7).
// ---------------------------------------------------------------------------
struct GArgs {
  const float* A; const float* B; float* C;
  int lda, ldb, ldc, K;
  float alpha;
  const float* C1; float b1; int ldc1;
  const float* C2; float b2; int ldc2;
  const float* r1u; const float* r1v; float r1c;
  const float* radd; float raddc;
  float addI;
  float* Cp; size_t mn; int pn;      // partial-mode
  float* out2; float sc2, dg2;       // second output (combine only)
};

template <bool AKM, bool BT>
__global__ __launch_bounds__(256)
void gemm_k(GArgs g) {
  __shared__ __align__(16) float AsRaw[2304]; // AKM: [32][68]; !AKM: [64][36]
  __shared__ __align__(16) float Bs[2176];    // [32][68]
  const int tid = threadIdx.x;
  const int tx = tid & 15, ty = tid >> 4;
  const int i0 = blockIdx.x * 64, j0 = blockIdx.y * 64;
  const int ks = gridDim.z;
  const int Kc = g.K / ks;
  const int kbeg = blockIdx.z * Kc, kend = kbeg + Kc;
  float acc[4][4] = {};
  for (int k0 = kbeg; k0 < kend; k0 += 32) {
    if (AKM) {
#pragma unroll
      for (int p = 0; p < 2; ++p) {
        int f4 = tid + p * 256;
        int kk = f4 >> 4, i4 = f4 & 15;
        *(float4*)(AsRaw + kk * 68 + i4 * 4) =
            *(const float4*)(g.A + (size_t)(k0 + kk) * g.lda + i0 + i4 * 4);
      }
    } else {
#pragma unroll
      for (int p = 0; p < 2; ++p) {
        int f4 = tid + p * 256;
        int ii = f4 >> 3, k4 = f4 & 7;
        *(float4*)(AsRaw + ii * 36 + k4 * 4) =
            *(const float4*)(g.A + (size_t)(i0 + ii) * g.lda + k0 + k4 * 4);
      }
    }
    if (BT) {
#pragma unroll
      for (int p = 0; p < 8; ++p) {
        int idx = tid + p * 256;
        int jj = idx >> 5, kk = idx & 31;
        Bs[kk * 68 + jj] = g.B[(size_t)(j0 + jj) * g.ldb + k0 + kk];
      }
    } else {
#pragma unroll
      for (int p = 0; p < 2; ++p) {
        int f4 = tid + p * 256;
        int kk = f4 >> 4, j4 = f4 & 15;
        *(float4*)(Bs + kk * 68 + j4 * 4) =
            *(const float4*)(g.B + (size_t)(k0 + kk) * g.ldb + j0 + j4 * 4);
      }
    }
    __syncthreads();
#pragma unroll 8
    for (int kk = 0; kk < 32; ++kk) {
      float ra[4], rb[4];
      if (AKM) {
        const float4 va = *(const float4*)(AsRaw + kk * 68 + ty * 4);
        ra[0] = va.x; ra[1] = va.y; ra[2] = va.z; ra[3] = va.w;
      } else {
#pragma unroll
        for (int r = 0; r < 4; ++r) ra[r] = AsRaw[(ty * 4 + r) * 36 + kk];
      }
      const float4 vb = *(const float4*)(Bs + kk * 68 + tx * 4);
      rb[0] = vb.x; rb[1] = vb.y; rb[2] = vb.z; rb[3] = vb.w;
#pragma unroll
      for (int r = 0; r < 4; ++r)
#pragma unroll
        for (int c = 0; c < 4; ++c) acc[r][c] += ra[r] * rb[c];
    }
    __syncthreads();
  }
  if (ks > 1) {
    float* dst = g.Cp + (size_t)blockIdx.z * g.mn;
#pragma unroll
    for (int r = 0; r < 4; ++r)
#pragma unroll
      for (int c = 0; c < 4; ++c) {
        int gi = i0 + ty * 4 + r, gj = j0 + tx * 4 + c;
        dst[(size_t)gi * g.pn + gj] = g.alpha * acc[r][c];
      }
  } else {
#pragma unroll
    for (int r = 0; r < 4; ++r)
#pragma unroll
      for (int c = 0; c < 4; ++c) {
        int gi = i0 + ty * 4 + r, gj = j0 + tx * 4 + c;
        float v = g.alpha * acc[r][c];
        if (g.C1) v += g.b1 * g.C1[(size_t)gi * g.ldc1 + gj];
        if (g.C2) v += g.b2 * g.C2[(size_t)gi * g.ldc2 + gj];
        if (g.r1u) v += g.r1c * g.r1u[gi] * g.r1v[gj];
        if (g.radd) v += g.raddc * g.radd[gj];
        if (g.addI != 0.0f && gi == gj) v += g.addI;
        g.C[(size_t)gi * g.ldc + gj] = v;
      }
  }
}

struct CArgs {
  const float* P; float* C; size_t mn; int N, ldc, ks;
  const float* C1; float b1; int ldc1;
  const float* C2; float b2; int ldc2;
  const float* r1u; const float* r1v; float r1c;
  const float* radd; float raddc;
  float addI;
  float* out2; float sc2, dg2;
};

__global__ __launch_bounds__(256)
void combine_k(CArgs c) {
  size_t idx = (size_t)blockIdx.x * 256 + threadIdx.x;
  if (idx >= c.mn) return;
  int i = (int)(idx / c.N), j = (int)(idx % c.N);
  float s = 0.0f;
  for (int z = 0; z < c.ks; ++z) s += c.P[(size_t)z * c.mn + idx];
  if (c.C1) s += c.b1 * c.C1[(size_t)i * c.ldc1 + j];
  if (c.C2) s += c.b2 * c.C2[(size_t)i * c.ldc2 + j];
  if (c.r1u) s += c.r1c * c.r1u[i] * c.r1v[j];
  if (c.radd) s += c.raddc * c.radd[j];
  if (c.addI != 0.0f && i == j) s += c.addI;
  c.C[(size_t)i * c.ldc + j] = s;
  if (c.out2) c.out2[(size_t)i * c.N + j] = s * c.sc2 + ((i == j) ? c.dg2 : 0.0f);
}

__global__ __launch_bounds__(256)
void scaleshift_k(const float* in, float* out, int n, float sc, float dg) {
  size_t idx = (size_t)blockIdx.x * 256 + threadIdx.x;
  if (idx >= (size_t)n * n) return;
  int i = (int)(idx / n), j = (int)(idx % n);
  out[idx] = in[idx] * sc + ((i == j) ? dg : 0.0f);
}

__global__ __launch_bounds__(256)
void symscale_k(const float* in, float* out, int n, float sc, float dg) {
  size_t idx = (size_t)blockIdx.x * 256 + threadIdx.x;
  if (idx >= (size_t)n * n) return;
  int i = (int)(idx / n), j = (int)(idx % n);
  out[idx] = 0.5f * (in[idx] + in[(size_t)j * n + i]) * sc + ((i == j) ? dg : 0.0f);
}

// ---------------------------------------------------------------------------
__global__ __launch_bounds__(256)
void colmean_part_k(const float* x, double* part) {
  int col = blockIdx.x * 256 + threadIdx.x;
  int rs = blockIdx.y;
  double acc = 0.0;
  for (int r = rs * 512; r < (rs + 1) * 512; ++r)
    acc += (double)x[(size_t)r * D_N + col];
  part[(size_t)rs * D_N + col] = acc;
}

__global__ __launch_bounds__(256)
void colmean_comb_k(const double* part, float* m) {
  int col = blockIdx.x * 256 + threadIdx.x;
  double acc = 0.0;
  for (int rs = 0; rs < 16; ++rs) acc += part[(size_t)rs * D_N + col];
  m[col] = (float)(acc / (double)B_N);
}

__global__ void inits_k(float* S, int n, unsigned seed) {
  int i = blockIdx.x * 256 + threadIdx.x;
  if (i < n) S[i] = hashf((unsigned)i * 2654435761u + seed);
}

// ---------------------------------------------------------------------------
// Blocked LDL^T of a 128x128 SPD matrix in LDS (pitch 129 = conflict-free).
// Panel (NB=16) factored in registers by wave 0 via __shfl; trailing rank-16
// update GEMM-style. 512 threads. D stored to Dsh. (validated v7, pitch fixed)
// ---------------------------------------------------------------------------
__device__ __forceinline__
void ldl128(float (&A)[128][129], float* Dsh, int tid) {
  for (int b = 0; b < 8; ++b) {
    const int o = b * 16;
    if (tid < 64) {
      const int lane = tid;
      float ra[16], rb[16], Dv[16];
#pragma unroll
      for (int q = 0; q < 16; ++q) {
        ra[q] = A[lane][o + q];
        rb[q] = A[lane + 64][o + q];
      }
#pragma unroll
      for (int jj = 0; jj < 16; ++jj) {
        const int c = o + jj;
        float pj = (c < 64) ? __shfl(ra[jj], c) : __shfl(rb[jj], c - 64);
        pj = fmaxf(pj, 1e-30f);
        Dv[jj] = pj;
        const float rdj = 1.0f / pj;
        const float ua = ra[jj] * rdj;
        const float ub = rb[jj] * rdj;
#pragma unroll
        for (int t = jj + 1; t < 16; ++t) {
          const int rt = o + t;
          float atj = (rt < 64) ? __shfl(ra[jj], rt) : __shfl(rb[jj], rt - 64);
          ra[t] -= ua * atj;
          rb[t] -= ub * atj;
        }
        ra[jj] = ua; rb[jj] = ub;
      }
#pragma unroll
      for (int q = 0; q < 16; ++q) {
        A[lane][o + q] = ra[q];
        A[lane + 64][o + q] = rb[q];
      }
      // static-index Dsh writes (avoid runtime-indexed register array)
#pragma unroll
      for (int q = 0; q < 16; ++q)
        if (lane == q) Dsh[o + q] = Dv[q];
    }
    __syncthreads();
    if (o + 16 < 128) {
      const int tx = tid & 15, ty = tid >> 4;  // 16 x 32 thread grid
      for (int i = o + 16 + ty; i < 128; i += 32) {
        float w[16];
#pragma unroll
        for (int q = 0; q < 16; ++q) w[q] = A[i][o + q] * Dsh[o + q];
        for (int t = o + 16 + tx; t <= i; t += 16) {
          float s = A[i][t];
#pragma unroll
          for (int q = 0; q < 16; ++q) s -= w[q] * A[t][o + q];
          A[i][t] = s;
        }
      }
    }
    __syncthreads();
  }
}

// Full chol + triangular inverse: A (in: SPD, out: chol L), Bm (out:
// Bm[c][i] = Linv[i][c], upper zero), Dsh (out: LDL diag). 512 threads.
__device__ __forceinline__
void cholinv128(float (&A)[128][129], float (&Bm)[128][129],
                float (&Y)[64][65], float* Dsh, float* sqv, int tid) {
  for (int idx = tid; idx < 128 * 129; idx += 512)
    (&Bm[0][0])[idx] = 0.0f;
  __syncthreads();
  ldl128(A, Dsh, tid);
  if (tid < 128) sqv[tid] = sqrtf(Dsh[tid]);
  __syncthreads();
  for (int idx = tid; idx < 128 * 128; idx += 512) {
    int i = idx >> 7, j = idx & 127;
    if (j <= i) A[i][j] *= sqv[j];
  }
  __syncthreads();
  if (tid < 128) {
    const int ob = (tid >> 6) * 64;
    const int c = tid & 63;
    for (int i = c; i < 64; ++i) {
      float s = (i == c) ? 1.0f : 0.0f;
      for (int t = c; t < i; ++t) s -= A[ob + i][ob + t] * Bm[ob + c][ob + t];
      Bm[ob + c][ob + i] = s / A[ob + i][ob + i];
    }
  }
  __syncthreads();
  for (int idx = tid; idx < 64 * 64; idx += 512) {
    int t = idx >> 6, c = idx & 63;
    float s = 0.0f;
    for (int s2 = c; s2 < 64; ++s2) s += A[64 + t][s2] * Bm[c][s2];
    Y[t][c] = s;
  }
  __syncthreads();
  for (int idx = tid; idx < 64 * 64; idx += 512) {
    int a = idx >> 6, c = idx & 63;
    float s = 0.0f;
    for (int t = 0; t <= a; ++t) s -= Bm[64 + t][64 + a] * Y[t][c];
    Bm[c][64 + a] = s;
  }
  __syncthreads();
}

// ---------------------------------------------------------------------------
// chol128_k: standalone chol+inv (+ optional logdet, Sinv). 512 threads.
// ---------------------------------------------------------------------------
__global__ __launch_bounds__(512)
void chol128_k(const float* Gin, int ldg, float* LinvT, double* logdet, float* Sinv) {
  __shared__ float A[128][129];
  __shared__ float Bm[128][129];
  __shared__ float Y[64][65];
  __shared__ float Dsh[128], sqv[128];
  const int tid = threadIdx.x;
  for (int idx = tid; idx < 128 * 128; idx += 512)
    A[idx >> 7][idx & 127] = Gin[(size_t)(idx >> 7) * ldg + (idx & 127)];
  __syncthreads();
  cholinv128(A, Bm, Y, Dsh, sqv, tid);
  if (logdet && tid == 0) {
    double s = 0.0;
    for (int j = 0; j < 128; ++j) s += log((double)Dsh[j]);
    *logdet = s;
  }
  if (LinvT)
    for (int idx = tid; idx < 128 * 128; idx += 512)
      LinvT[idx] = Bm[idx >> 7][idx & 127];
  if (Sinv)
    for (int idx = tid; idx < 128 * 128; idx += 512) {
      int i = idx >> 7, j = idx & 127;
      int t0 = (i > j) ? i : j;
      float s = 0.0f;
      for (int t = t0; t < 128; ++t) s += Bm[i][t] * Bm[j][t];
      Sinv[idx] = s;
    }
}

// ---------------------------------------------------------------------------
// qrf_k: fused blocked CholQR-256 small-matrix phase. Input Gram G (256x256,
// ldg), output Rinv (256x256 row-major) with R = chol(G)^T:
//   Rinv = [[L11^-T, -L11^-T L21^T L22^-T], [0, L22^-T]]
// Pg: 128x128 global scratch for L21. One WG, 512 threads. In-kernel 128^3
// matmuls use strided register micro-tiles (8 rows x 4 cols per thread),
// conflict-free LDS access at pitch 129.
// ---------------------------------------------------------------------------
__global__ __launch_bounds__(512)
void qrf_k(const float* G, int ldg, float* Rinv, float* Pg) {
  __shared__ float A[128][129];
  __shared__ float Bm[128][129];
  __shared__ float Y[64][65];
  __shared__ float Dsh[128], sqv[128];
  const int tid = threadIdx.x;
  const int jl = tid & 31;        // j(c) = jl + 32c, c<4
  const int il = tid >> 5;        // i(r) = il + 16r, r<8
  // phase 1: chol+inv of G11
  for (int idx = tid; idx < 128 * 128; idx += 512)
    A[idx >> 7][idx & 127] = G[(size_t)(idx >> 7) * ldg + (idx & 127)];
  __syncthreads();
  cholinv128(A, Bm, Y, Dsh, sqv, tid);
  // Rinv TL = L11^-T: Rinv[k][j] = Linv11[j][k] = Bm[k][j]; BL = 0
  for (int idx = tid; idx < 128 * 128; idx += 512) {
    int k = idx >> 7, j = idx & 127;
    Rinv[(size_t)k * 256 + j] = Bm[k][j];
    Rinv[(size_t)(128 + k) * 256 + j] = 0.0f;
  }
  __syncthreads();
  // phase 2: L21[i][j] = sum_t G21[i][t] * Bm[t][j]  -> A and Pg
  {
    float acc[8][4] = {};
    for (int t = 0; t < 128; ++t) {
      float bv[4];
#pragma unroll
      for (int c = 0; c < 4; ++c) bv[c] = Bm[t][jl + 32 * c];
#pragma unroll
      for (int r = 0; r < 8; ++r) {
        float gv = G[(size_t)(128 + il + 16 * r) * ldg + t];
#pragma unroll
        for (int c = 0; c < 4; ++c) acc[r][c] += gv * bv[c];
      }
    }
    __syncthreads();
#pragma unroll
    for (int r = 0; r < 8; ++r)
#pragma unroll
      for (int c = 0; c < 4; ++c) {
        int i = il + 16 * r, j = jl + 32 * c;
        A[i][j] = acc[r][c];
        Pg[(size_t)i * 128 + j] = acc[r][c];
      }
  }
  __syncthreads();
  // phase 3: Schur[i][j] = G22[i][j] - sum_t A[i][t]*A[j][t]  -> Bm
  {
    float acc[8][4] = {};
    for (int t = 0; t < 128; ++t) {
      float bv[4];
#pragma unroll
      for (int c = 0; c < 4; ++c) bv[c] = A[jl + 32 * c][t];
#pragma unroll
      for (int r = 0; r < 8; ++r) {
        float av = A[il + 16 * r][t];
#pragma unroll
        for (int c = 0; c < 4; ++c) acc[r][c] += av * bv[c];
      }
    }
    __syncthreads();
#pragma unroll
    for (int r = 0; r < 8; ++r)
#pragma unroll
      for (int c = 0; c < 4; ++c) {
        int i = il + 16 * r, j = jl + 32 * c;
        Bm[i][j] = G[(size_t)(128 + i) * ldg + 128 + j] - acc[r][c];
      }
  }
  __syncthreads();
  // phase 4: A <- Schur; chol+inv -> Bm = Li22T; Rinv BR
  for (int idx = tid; idx < 128 * 128; idx += 512) {
    int i = idx >> 7, j = idx & 127;
    float v = Bm[i][j];
    __syncthreads();  // note: uniform loop, all threads hit this together
    A[i][j] = v;
    __syncthreads();
  }
  __syncthreads();
  cholinv128(A, Bm, Y, Dsh, sqv, tid);
  for (int idx = tid; idx < 128 * 128; idx += 512) {
    int k = idx >> 7, j = idx & 127;
    Rinv[(size_t)(128 + k) * 256 + 128 + j] = Bm[k][j];
  }
  __syncthreads();
  // phase 5: M1[t][j] = sum_s Pg[s][t] * Bm[s][j]   (M1 = L21^T * L22^-T) -> A
  {
    float acc[8][4] = {};
    for (int s = 0; s < 128; ++s) {
      float bv[4];
#pragma unroll
      for (int c = 0; c < 4; ++c) bv[c] = Bm[s][jl + 32 * c];
#pragma unroll
      for (int r = 0; r < 8; ++r) {
        float pv = Pg[(size_t)s * 128 + il + 16 * r];
#pragma unroll
        for (int c = 0; c < 4; ++c) acc[r][c] += pv * bv[c];
      }
    }
    __syncthreads();
#pragma unroll
    for (int r = 0; r < 8; ++r)
#pragma unroll
      for (int c = 0; c < 4; ++c)
        A[il + 16 * r][jl + 32 * c] = acc[r][c];
  }
  __syncthreads();
  // phase 6: X[k][j] = -sum_t Linv11[t][k]*M1[t][j] = -sum_t RinvTL[k][t]*A[t][j]
  {
    float acc[8][4] = {};
    for (int t = 0; t < 128; ++t) {
      float bv[4];
#pragma unroll
      for (int c = 0; c < 4; ++c) bv[c] = A[t][jl + 32 * c];
#pragma unroll
      for (int r = 0; r < 8; ++r) {
        float rv = Rinv[(size_t)(il + 16 * r) * 256 + t];
#pragma unroll
        for (int c = 0; c < 4; ++c) acc[r][c] += rv * bv[c];
      }
    }
#pragma unroll
    for (int r = 0; r < 8; ++r)
#pragma unroll
      for (int c = 0; c < 4; ++c)
        Rinv[(size_t)(il + 16 * r) * 256 + 128 + jl + 32 * c] = -acc[r][c];
  }
}

__global__ __launch_bounds__(128)
void mw_k(const float* m, const float* W, float* mW) {
  int j = threadIdx.x;
  double acc = 0.0;
  for (int c = 0; c < D_N; ++c) acc += (double)m[c] * (double)W[(size_t)c * K_N + j];
  mW[j] = (float)acc;
}

// ---------------------------------------------------------------------------
__global__ __launch_bounds__(256)
void count_sort_k(const int* lab, int* perm, int* counts, int* offs) {
  __shared__ int cnt[NLAB][256];
  __shared__ int labOff[NLAB + 1];
  const int tid = threadIdx.x;
  int lc[NLAB];
#pragma unroll
  for (int l = 0; l < NLAB; ++l) lc[l] = 0;
  for (int r = tid * 32; r < tid * 32 + 32; ++r) {
    int l = lab[r]; l = (l < 0) ? 0 : (l > 9 ? 9 : l);
    lc[l]++;
  }
#pragma unroll
  for (int l = 0; l < NLAB; ++l) cnt[l][tid] = lc[l];
  __syncthreads();
  if (tid < NLAB) {
    int run = 0;
    for (int i = 0; i < 256; ++i) { int v = cnt[tid][i]; cnt[tid][i] = run; run += v; }
    counts[tid] = run;
  }
  __syncthreads();
  if (tid == 0) {
    int run = 0;
    for (int l = 0; l < NLAB; ++l) { labOff[l] = run; run += counts[l]; }
    labOff[NLAB] = run;
    for (int l = 0; l <= NLAB; ++l) offs[l] = labOff[l];
  }
  __syncthreads();
  int lc2[NLAB];
#pragma unroll
  for (int l = 0; l < NLAB; ++l) lc2[l] = 0;
  for (int r = tid * 32; r < tid * 32 + 32; ++r) {
    int l = lab[r]; l = (l < 0) ? 0 : (l > 9 ? 9 : l);
    int pos = labOff[l] + cnt[l][tid] + lc2[l];
    lc2[l]++;
    perm[pos] = r;
  }
}

__global__ __launch_bounds__(256)
void gather_k(const float* z, const int* perm, float* zs) {
  int g = blockIdx.x * 256 + threadIdx.x;
  int row = g >> 5, q = g & 31;
  const float4* zf = (const float4*)z;
  float4* of = (float4*)zs;
  of[(size_t)row * 32 + q] = zf[(size_t)perm[row] * 32 + q];
}

__global__ __launch_bounds__(128)
void labstat_part_k(const float* zs, const int* offs, double* part) {
  int l = blockIdx.x >> 3, s = blockIdx.x & 7;
  int j = threadIdx.x;
  int r0, r1;
  if (l < NLAB) {
    int st = offs[l], en = offs[l + 1], len = en - st;
    r0 = st + (int)(((long long)len * s) >> 3);
    r1 = st + (int)(((long long)len * (s + 1)) >> 3);
  } else {
    r0 = s * 1024; r1 = r0 + 1024;
  }
  double acc = 0.0;
  for (int r = r0; r < r1; ++r) acc += (double)zs[(size_t)r * K_N + j];
  part[((size_t)l * 8 + s) * K_N + j] = acc;
}

__global__ __launch_bounds__(128)
void labstat_comb_k(const double* part, float* sum_mu, float* muT) {
  int j = threadIdx.x;
  for (int l = 0; l < NLAB; ++l) {
    double a = 0.0;
    for (int s = 0; s < 8; ++s) a += part[((size_t)l * 8 + s) * K_N + j];
    sum_mu[l * K_N + j] = (float)a;
  }
  double t = 0.0;
  for (int s = 0; s < 8; ++s) t += part[((size_t)NLAB * 8 + s) * K_N + j];
  muT[j] = (float)(t / (double)B_N);
}

__global__ __launch_bounds__(256)
void sigsum_k(const float* zs, const int* offs, const float* muT, float* SigS) {
  int l = blockIdx.x >> 2, t = blockIdx.x & 3;
  int i0 = (t >> 1) * 64, j0 = (t & 1) * 64;
  __shared__ float Zi[32][66], Zj[32][66];
  __shared__ float muL[128];
  int tid = threadIdx.x, tx = tid & 15, ty = tid >> 4;
  if (tid < 128) muL[tid] = muT[tid];
  __syncthreads();
  int start = offs[l], end = offs[l + 1];
  float acc[4][4] = {};
  for (int base = start; base < end; base += 32) {
#pragma unroll
    for (int p = 0; p < 8; ++p) {
      int idx = tid + p * 256;
      int rr = idx >> 6, cc = idx & 63;
      int r = base + rr;
      float vi = 0.0f, vj = 0.0f;
      if (r < end) {
        vi = zs[(size_t)r * K_N + i0 + cc] - muL[i0 + cc];
        vj = zs[(size_t)r * K_N + j0 + cc] - muL[j0 + cc];
      }
      Zi[rr][cc] = vi; Zj[rr][cc] = vj;
    }
    __syncthreads();
    for (int rr = 0; rr < 32; ++rr) {
      float ra[4], rb[4];
#pragma unroll
      for (int r = 0; r < 4; ++r) ra[r] = Zi[rr][ty * 4 + r];
#pragma unroll
      for (int c = 0; c < 4; ++c) rb[c] = Zj[rr][tx * 4 + c];
#pragma unroll
      for (int r = 0; r < 4; ++r)
#pragma unroll
        for (int c = 0; c < 4; ++c) acc[r][c] += ra[r] * rb[c];
    }
    __syncthreads();
  }
#pragma unroll
  for (int r = 0; r < 4; ++r)
#pragma unroll
    for (int c = 0; c < 4; ++c)
      SigS[((size_t)l * K_N + i0 + ty * 4 + r) * K_N + j0 + tx * 4 + c] = acc[r][c];
}

__global__ __launch_bounds__(256)
void sigt_comb_k(const float* SigS, float* SigT) {
  int idx = blockIdx.x * 256 + threadIdx.x;
  int i = idx >> 7, j = idx & 127;
  double s = 0.0;
  for (int l = 0; l < NLAB; ++l) s += (double)SigS[(size_t)l * 16384 + idx];
  SigT[idx] = (float)(s / (double)B_N) + ((i == j) ? 1.0f : 0.0f);
}

// ---------------------------------------------------------------------------
__global__ __launch_bounds__(512)
void perlabel_k(const float* SigS, const float* Sinv, const float* mu,
                const float* sum_mu, const int* counts, const double* logdet_t,
                double* klout, int* present) {
  int l = blockIdx.x, tid = threadIdx.x;
  __shared__ float Amat[128][129];
  __shared__ double red[512];
  __shared__ float dv[128];
  __shared__ float Dsh[128];
  int cnt = counts[l];
  float sc = (cnt > 0) ? (float)cnt : 1.0f;
  for (int idx = tid; idx < 128 * 128; idx += 512) {
    int i = idx >> 7, j = idx & 127;
    Amat[i][j] = SigS[((size_t)l * K_N + i) * K_N + j] / sc + ((i == j) ? 1.0f : 0.0f);
  }
  if (tid < 128) dv[tid] = mu[tid] - sum_mu[l * K_N + tid] / sc;
  __syncthreads();
  double tr = 0.0, mh = 0.0;
  for (int idx = tid; idx < 128 * 128; idx += 512) {
    int i = idx >> 7, j = idx & 127;
    double sv = (double)Sinv[idx];
    tr += sv * (double)Amat[i][j];
    mh += sv * (double)dv[i] * (double)dv[j];
  }
  red[tid] = tr; __syncthreads();
  for (int off = 256; off > 0; off >>= 1) { if (tid < off) red[tid] += red[tid + off]; __syncthreads(); }
  double trv = red[0]; __syncthreads();
  red[tid] = mh; __syncthreads();
  for (int off = 256; off > 0; off >>= 1) { if (tid < off) red[tid] += red[tid + off]; __syncthreads(); }
  double mhv = red[0]; __syncthreads();
  ldl128(Amat, Dsh, tid);
  if (tid == 0) {
    double ld = 0.0;
    for (int j = 0; j < 128; ++j) ld += log((double)Dsh[j]);
    klout[l] = 0.5 * (trv + mhv - 128.0 + logdet_t[0] - ld);
    present[l] = (cnt > 0) ? 1 : 0;
  }
}

__global__ void finalize_k(const double* kl, const int* present, float* out) {
  if (threadIdx.x == 0 && blockIdx.x == 0) {
    double s = 0.0; int np = 0;
    for (int l = 0; l < NLAB; ++l)
      if (present[l]) { s += kl[l]; np++; }
    out[0] = (float)((np > 0) ? s / ((double)np * (double)B_N) : 0.0);
  }
}

// ===========================================================================
// Host side
// ===========================================================================
static inline GArgs mkg(const float* A, int lda, const float* B, int ldb,
                        float* C, int ldc, int K, float alpha) {
  GArgs g{};
  g.A = A; g.B = B; g.C = C; g.lda = lda; g.ldb = ldb; g.ldc = ldc;
  g.K = K; g.alpha = alpha;
  return g;
}

static inline void run_g(hipStream_t st, bool akm, bool bt, GArgs g,
                         int M, int N, int ks, float* Ppart) {
  if (ks > 1) {
    g.Cp = Ppart; g.mn = (size_t)M * N; g.pn = N;
    dim3 grid(M / 64, N / 64, ks);
    if (akm)     hipLaunchKernelGGL((gemm_k<true, false>),  grid, dim3(256), 0, st, g);
    else if (bt) hipLaunchKernelGGL((gemm_k<false, true>),  grid, dim3(256), 0, st, g);
    else         hipLaunchKernelGGL((gemm_k<false, false>), grid, dim3(256), 0, st, g);
    CArgs c{Ppart, g.C, (size_t)M * N, N, g.ldc, ks,
            g.C1, g.b1, g.ldc1, g.C2, g.b2, g.ldc2,
            g.r1u, g.r1v, g.r1c, g.radd, g.raddc, g.addI,
            g.out2, g.sc2, g.dg2};
    hipLaunchKernelGGL(combine_k, dim3((unsigned)(((size_t)M * N + 255) / 256)),
                       dim3(256), 0, st, c);
  } else {
    dim3 grid(M / 64, N / 64);
    if (akm)     hipLaunchKernelGGL((gemm_k<true, false>),  grid, dim3(256), 0, st, g);
    else if (bt) hipLaunchKernelGGL((gemm_k<false, true>),  grid, dim3(256), 0, st, g);
    else         hipLaunchKernelGGL((gemm_k<false, false>), grid, dim3(256), 0, st, g);
  }
}

extern "C" void kernel_launch(void* const* d_in, const int* in_sizes, int n_in,
                              void* d_out, int out_size, void* d_ws, size_t ws_size,
                              hipStream_t stream) {
  const float* x = (const float*)d_in[0];
  const int* lab = (const int*)d_in[1];
  float* out = (float*)d_out;

  size_t off = 0;
  auto alloc = [&](size_t nbytes) -> void* {
    void* r = (void*)((char*)d_ws + off);
    off += ((nbytes + 255) / 256) * 256;
    return r;
  };
  float*  m     = (float*) alloc(D_N * 4);
  float*  Cn    = (float*) alloc((size_t)D_N * D_N * 4);
  float*  At    = (float*) alloc((size_t)D_N * D_N * 4);  // Atilde -> T4 -> zs
  float*  T2    = (float*) alloc((size_t)D_N * D_N * 4);  // T2 -> z
  float*  Fo    = (float*) alloc((size_t)D_N * D_N * 4);  // outer filter T6
  float*  SA    = (float*) alloc((size_t)D_N * M_N * 4);
  float*  SB    = (float*) alloc((size_t)D_N * M_N * 4);
  float*  SC    = (float*) alloc((size_t)D_N * M_N * 4);
  float*  G256  = (float*) alloc((size_t)M_N * M_N * 4);  // -> F12i
  float*  Tm    = (float*) alloc((size_t)M_N * M_N * 4);
  float*  Rb    = (float*) alloc((size_t)M_N * M_N * 4);  // Rinv from qrf
  float*  Pg2   = (float*) alloc((size_t)K_N * K_N * 4);  // qrf scratch (L21)
  float*  Tt    = (float*) alloc((size_t)M_N * M_N * 4);
  float*  T2i   = (float*) alloc((size_t)M_N * M_N * 4);
  float*  T4i   = (float*) alloc((size_t)M_N * M_N * 4);
  float*  F6i   = (float*) alloc((size_t)M_N * M_N * 4);
  float*  VA    = (float*) alloc((size_t)M_N * K_N * 4);
  float*  VB    = (float*) alloc((size_t)M_N * K_N * 4);
  float*  G128  = (float*) alloc((size_t)K_N * K_N * 4);
  float*  Li128 = (float*) alloc((size_t)K_N * K_N * 4);
  float*  Wa    = (float*) alloc((size_t)D_N * K_N * 4);
  float*  Wb    = (float*) alloc((size_t)D_N * K_N * 4);
  float*  mW    = (float*) alloc(K_N * 4);
  double* partM = (double*)alloc((size_t)16 * D_N * 8);
  double* partL = (double*)alloc((size_t)11 * 8 * K_N * 8);
  float*  sumMu = (float*) alloc(NLAB * K_N * 4);
  float*  muT   = (float*) alloc(K_N * 4);
  float*  SigT  = (float*) alloc((size_t)K_N * K_N * 4);
  float*  Sinv  = (float*) alloc((size_t)K_N * K_N * 4);
  float*  SigS  = (float*) alloc((size_t)NLAB * K_N * K_N * 4);
  double* logdet_t = (double*)alloc(16);
  double* klv      = (double*)alloc(NLAB * 8);
  int*    counts = (int*)alloc(16 * 4);
  int*    offs   = (int*)alloc(16 * 4);
  int*    present= (int*)alloc(16 * 4);
  int*    perm   = (int*)alloc(B_N * 4);
  float*  T4   = At;    // alias: At dead once T2 exists
  float*  F12i = G256;  // alias: G256 dead after outer segs
  float*  zs   = At;    // alias: T4 dead after Fo; zs written step 9
  float*  z    = T2;    // alias: T2 dead after Fo
  size_t rem = (ws_size > off) ? (ws_size - off) : 0;
  int KS = 1, KSC = 1;
  size_t pbytes = 0;
  if (rem >= (size_t)33 * 1024 * 1024)      { KSC = 8; KS = 4; pbytes = (size_t)32 * 1024 * 1024; }
  else if (rem >= (size_t)17 * 1024 * 1024) { KSC = 4; KS = 4; pbytes = (size_t)16 * 1024 * 1024; }
  else if (rem >= (size_t)9 * 1024 * 1024)  { KSC = 2; KS = 2; pbytes = (size_t)8 * 1024 * 1024; }
  float* Ppart = pbytes ? (float*)alloc(pbytes) : nullptr;
  const int gks = (KS >= 4) ? 8 : KS;   // split factor for small-output Grams
  (void)in_sizes; (void)n_in; (void)out_size;

  // 1) column means; Cn = x^T x / B - m m^T ; At = 1.6*Cn - I (fused)
  hipLaunchKernelGGL(colmean_part_k, dim3(4, 16), dim3(256), 0, stream, x, partM);
  hipLaunchKernelGGL(colmean_comb_k, dim3(4), dim3(256), 0, stream, partM, m);
  {
    GArgs g = mkg(x, D_N, x, D_N, Cn, D_N, B_N, 1.0f / (float)B_N);
    g.r1u = m; g.r1v = m; g.r1c = -1.0f;
    if (KSC > 1) { g.out2 = At; g.sc2 = 1.6f; g.dg2 = -1.0f; }
    run_g(stream, true, false, g, D_N, D_N, KSC, Ppart);
    if (KSC == 1)
      hipLaunchKernelGGL(scaleshift_k, dim3((D_N * D_N + 255) / 256), dim3(256),
                         0, stream, Cn, At, D_N, 1.6f, -1.0f);
  }

  // 2) Outer filter Fo = T6(At) = 2*T2*T4 - T2, band [0,1.25] (c=d=0.625)
  {
    GArgs g = mkg(At, D_N, At, D_N, T2, D_N, D_N, 2.0f);  // T2 = 2 At^2 - I
    g.addI = -1.0f;
    run_g(stream, true, false, g, D_N, D_N, KS, Ppart);
    g = mkg(T2, D_N, T2, D_N, T4, D_N, D_N, 2.0f);        // T4 = 2 T2^2 - I
    g.addI = -1.0f;
    run_g(stream, true, false, g, D_N, D_N, KS, Ppart);
    g = mkg(T2, D_N, T4, D_N, Fo, D_N, D_N, 2.0f);        // T6 = 2 T2 T4 - T2
    g.C1 = T2; g.b1 = -1.0f; g.ldc1 = D_N;
    run_g(stream, true, false, g, D_N, D_N, KS, Ppart);
  }

  // Fused blocked CholQR-256: Gram -> qrf (Rinv) -> Snew = S * Rinv
  auto qr256 = [&](float* S, float* Snew) {
    GArgs g = mkg(S, M_N, S, M_N, G256, M_N, D_N, 1.0f);
    run_g(stream, true, false, g, M_N, M_N, gks, Ppart);
    hipLaunchKernelGGL(qrf_k, dim3(1), dim3(512), 0, stream, G256, M_N, Rb, Pg2);
    g = mkg(S, M_N, Rb, M_N, Snew, M_N, M_N, 1.0f);
    run_g(stream, false, false, g, D_N, M_N, KS, Ppart);
  };

  // 3) Outer: 2 segments of {S <- Fo @ S ; CholQR-256}
  hipLaunchKernelGGL(inits_k, dim3((D_N * M_N + 255) / 256), dim3(256), 0, stream,
                     SA, D_N * M_N, 12345u);
  float* Scur = SA; float* t1 = SB; float* t2 = SC;
  for (int seg = 0; seg < 2; ++seg) {
    GArgs g = mkg(Fo, D_N, Scur, M_N, t1, M_N, D_N, 1.0f);
    run_g(stream, true, false, g, D_N, M_N, KS, Ppart);
    qr256(t1, t2);
    float* t = Scur; Scur = t2; t2 = t;
  }

  // 4) T = S^T (Cn S)
  {
    GArgs g = mkg(Cn, D_N, Scur, M_N, t1, M_N, D_N, 1.0f);
    run_g(stream, true, false, g, D_N, M_N, KS, Ppart);
    g = mkg(Scur, M_N, t1, M_N, Tm, M_N, D_N, 1.0f);
    run_g(stream, true, false, g, M_N, M_N, gks, Ppart);
  }

  // 5) Inner filter F12 = T12(Tt) = 2*T6(Tt)^2 - I, band [0,1.27] (c=d=0.635)
  hipLaunchKernelGGL(symscale_k, dim3((M_N * M_N + 255) / 256), dim3(256), 0,
                     stream, Tm, Tt, M_N, 1.0f / 0.635f, -1.0f);
  {
    GArgs g = mkg(Tt, M_N, Tt, M_N, T2i, M_N, M_N, 2.0f);
    g.addI = -1.0f;
    run_g(stream, true, false, g, M_N, M_N, 1, nullptr);
    g = mkg(T2i, M_N, T2i, M_N, T4i, M_N, M_N, 2.0f);
    g.addI = -1.0f;
    run_g(stream, true, false, g, M_N, M_N, 1, nullptr);
    g = mkg(T2i, M_N, T4i, M_N, F6i, M_N, M_N, 2.0f);
    g.C1 = T2i; g.b1 = -1.0f; g.ldc1 = M_N;
    run_g(stream, true, false, g, M_N, M_N, 1, nullptr);
    g = mkg(F6i, M_N, F6i, M_N, F12i, M_N, M_N, 2.0f);
    g.addI = -1.0f;
    run_g(stream, true, false, g, M_N, M_N, 1, nullptr);
  }

  // 6) Inner: 1 segment {V <- F12 @ V ; CholQR-128}
  hipLaunchKernelGGL(inits_k, dim3((M_N * K_N + 255) / 256), dim3(256), 0, stream,
                     VA, M_N * K_N, 777u);
  {
    GArgs g = mkg(F12i, M_N, VA, K_N, VB, K_N, M_N, 1.0f);
    run_g(stream, true, false, g, M_N, K_N, 1, nullptr);
    g = mkg(VB, K_N, VB, K_N, G128, K_N, M_N, 1.0f);
    run_g(stream, true, false, g, K_N, K_N, 1, nullptr);
    hipLaunchKernelGGL(chol128_k, dim3(1), dim3(512), 0, stream,
                       G128, K_N, Li128, (double*)nullptr, (float*)nullptr);
    g = mkg(VB, K_N, Li128, K_N, VA, K_N, K_N, 1.0f);
    run_g(stream, false, false, g, M_N, K_N, 1, nullptr);
  }

  // 7) W = S*V, exact CholQR-128 on W (CholQR2 pattern)
  {
    GArgs g = mkg(Scur, M_N, VA, K_N, Wa, K_N, M_N, 1.0f);
    run_g(stream, false, false, g, D_N, K_N, 1, nullptr);
    g = mkg(Wa, K_N, Wa, K_N, G128, K_N, D_N, 1.0f);
    run_g(stream, true, false, g, K_N, K_N, gks, Ppart);
    hipLaunchKernelGGL(chol128_k, dim3(1), dim3(512), 0, stream,
                       G128, K_N, Li128, (double*)nullptr, (float*)nullptr);
    g = mkg(Wa, K_N, Li128, K_N, Wb, K_N, K_N, 1.0f);
    run_g(stream, false, false, g, D_N, K_N, 1, nullptr);
  }

  // 8) z = x W - 1 (m^T W)
  hipLaunchKernelGGL(mw_k, dim3(1), dim3(128), 0, stream, m, Wb, mW);
  {
    GArgs g = mkg(x, D_N, Wb, K_N, z, K_N, D_N, 1.0f);
    g.radd = mW; g.raddc = -1.0f;
    run_g(stream, false, false, g, B_N, K_N, KS, Ppart);
  }

  // 9) sort rows by label; gather into zs
  hipLaunchKernelGGL(count_sort_k, dim3(1), dim3(256), 0, stream,
                     lab, perm, counts, offs);
  hipLaunchKernelGGL(gather_k, dim3(B_N * 32 / 256), dim3(256), 0, stream,
                     z, perm, zs);

  // 10) label and global column sums
  hipLaunchKernelGGL(labstat_part_k, dim3(11 * 8), dim3(128), 0, stream,
                     zs, offs, partL);
  hipLaunchKernelGGL(labstat_comb_k, dim3(1), dim3(128), 0, stream,
                     partL, sumMu, muT);

  // 11) per-label Sigma sums; SigT; Sinv + logdet
  hipLaunchKernelGGL(sigsum_k, dim3(NLAB * 4), dim3(256), 0, stream,
                     zs, offs, muT, SigS);
  hipLaunchKernelGGL(sigt_comb_k, dim3(64), dim3(256), 0, stream, SigS, SigT);
  hipLaunchKernelGGL(chol128_k, dim3(1), dim3(512), 0, stream,
                     SigT, K_N, (float*)nullptr, logdet_t, Sinv);

  // 12) per-label KL, reduce
  hipLaunchKernelGGL(perlabel_k, dim3(NLAB), dim3(512), 0, stream,
                     SigS, Sinv, muT, sumMu, counts, logdet_t, klv, present);
  hipLaunchKernelGGL(finalize_k, dim3(1), dim3(64), 0, stream, klv, present, out);
}

// Round 9
// 2486.060 us; speedup vs baseline: 1.0193x; 1.0193x over previous
//
#include <hip/hip_runtime.h>
#include <hip/hip_bf16.h>
#include <math.h>

// ============================================================================
// GMMLoss2_pca v9: qrf_k matmul phases now LDS-staged (chunked cooperative
// loads; no global reads in inner loops). Pipeline otherwise = v8.
// ============================================================================

#define B_N 8192
#define D_N 1024
#define K_N 128
#define M_N 256
#define NLAB 10

__device__ __forceinline__ float hashf(unsigned x) {
  x ^= x >> 16; x *= 0x7feb352du; x ^= x >> 15; x *= 0x846ca68bu; x ^= x >> 16;
  return (float)(x >> 8) * (1.0f / 16777216.0f) - 0.5f;
}

// ---------------------------------------------------------------------------
// Tiled f32 GEMM (validated v4-v8).
// ---------------------------------------------------------------------------
struct GArgs {
  const float* A; const float* B; float* C;
  int lda, ldb, ldc, K;
  float alpha;
  const float* C1; float b1; int ldc1;
  const float* C2; float b2; int ldc2;
  const float* r1u; const float* r1v; float r1c;
  const float* radd; float raddc;
  float addI;
  float* Cp; size_t mn; int pn;      // partial-mode
  float* out2; float sc2, dg2;       // second output (combine only)
};

template <bool AKM, bool BT>
__global__ __launch_bounds__(256)
void gemm_k(GArgs g) {
  __shared__ __align__(16) float AsRaw[2304]; // AKM: [32][68]; !AKM: [64][36]
  __shared__ __align__(16) float Bs[2176];    // [32][68]
  const int tid = threadIdx.x;
  const int tx = tid & 15, ty = tid >> 4;
  const int i0 = blockIdx.x * 64, j0 = blockIdx.y * 64;
  const int ks = gridDim.z;
  const int Kc = g.K / ks;
  const int kbeg = blockIdx.z * Kc, kend = kbeg + Kc;
  float acc[4][4] = {};
  for (int k0 = kbeg; k0 < kend; k0 += 32) {
    if (AKM) {
#pragma unroll
      for (int p = 0; p < 2; ++p) {
        int f4 = tid + p * 256;
        int kk = f4 >> 4, i4 = f4 & 15;
        *(float4*)(AsRaw + kk * 68 + i4 * 4) =
            *(const float4*)(g.A + (size_t)(k0 + kk) * g.lda + i0 + i4 * 4);
      }
    } else {
#pragma unroll
      for (int p = 0; p < 2; ++p) {
        int f4 = tid + p * 256;
        int ii = f4 >> 3, k4 = f4 & 7;
        *(float4*)(AsRaw + ii * 36 + k4 * 4) =
            *(const float4*)(g.A + (size_t)(i0 + ii) * g.lda + k0 + k4 * 4);
      }
    }
    if (BT) {
#pragma unroll
      for (int p = 0; p < 8; ++p) {
        int idx = tid + p * 256;
        int jj = idx >> 5, kk = idx & 31;
        Bs[kk * 68 + jj] = g.B[(size_t)(j0 + jj) * g.ldb + k0 + kk];
      }
    } else {
#pragma unroll
      for (int p = 0; p < 2; ++p) {
        int f4 = tid + p * 256;
        int kk = f4 >> 4, j4 = f4 & 15;
        *(float4*)(Bs + kk * 68 + j4 * 4) =
            *(const float4*)(g.B + (size_t)(k0 + kk) * g.ldb + j0 + j4 * 4);
      }
    }
    __syncthreads();
#pragma unroll 8
    for (int kk = 0; kk < 32; ++kk) {
      float ra[4], rb[4];
      if (AKM) {
        const float4 va = *(const float4*)(AsRaw + kk * 68 + ty * 4);
        ra[0] = va.x; ra[1] = va.y; ra[2] = va.z; ra[3] = va.w;
      } else {
#pragma unroll
        for (int r = 0; r < 4; ++r) ra[r] = AsRaw[(ty * 4 + r) * 36 + kk];
      }
      const float4 vb = *(const float4*)(Bs + kk * 68 + tx * 4);
      rb[0] = vb.x; rb[1] = vb.y; rb[2] = vb.z; rb[3] = vb.w;
#pragma unroll
      for (int r = 0; r < 4; ++r)
#pragma unroll
        for (int c = 0; c < 4; ++c) acc[r][c] += ra[r] * rb[c];
    }
    __syncthreads();
  }
  if (ks > 1) {
    float* dst = g.Cp + (size_t)blockIdx.z * g.mn;
#pragma unroll
    for (int r = 0; r < 4; ++r)
#pragma unroll
      for (int c = 0; c < 4; ++c) {
        int gi = i0 + ty * 4 + r, gj = j0 + tx * 4 + c;
        dst[(size_t)gi * g.pn + gj] = g.alpha * acc[r][c];
      }
  } else {
#pragma unroll
    for (int r = 0; r < 4; ++r)
#pragma unroll
      for (int c = 0; c < 4; ++c) {
        int gi = i0 + ty * 4 + r, gj = j0 + tx * 4 + c;
        float v = g.alpha * acc[r][c];
        if (g.C1) v += g.b1 * g.C1[(size_t)gi * g.ldc1 + gj];
        if (g.C2) v += g.b2 * g.C2[(size_t)gi * g.ldc2 + gj];
        if (g.r1u) v += g.r1c * g.r1u[gi] * g.r1v[gj];
        if (g.radd) v += g.raddc * g.radd[gj];
        if (g.addI != 0.0f && gi == gj) v += g.addI;
        g.C[(size_t)gi * g.ldc + gj] = v;
      }
  }
}

struct CArgs {
  const float* P; float* C; size_t mn; int N, ldc, ks;
  const float* C1; float b1; int ldc1;
  const float* C2; float b2; int ldc2;
  const float* r1u; const float* r1v; float r1c;
  const float* radd; float raddc;
  float addI;
  float* out2; float sc2, dg2;
};

__global__ __launch_bounds__(256)
void combine_k(CArgs c) {
  size_t idx = (size_t)blockIdx.x * 256 + threadIdx.x;
  if (idx >= c.mn) return;
  int i = (int)(idx / c.N), j = (int)(idx % c.N);
  float s = 0.0f;
  for (int z = 0; z < c.ks; ++z) s += c.P[(size_t)z * c.mn + idx];
  if (c.C1) s += c.b1 * c.C1[(size_t)i * c.ldc1 + j];
  if (c.C2) s += c.b2 * c.C2[(size_t)i * c.ldc2 + j];
  if (c.r1u) s += c.r1c * c.r1u[i] * c.r1v[j];
  if (c.radd) s += c.raddc * c.radd[j];
  if (c.addI != 0.0f && i == j) s += c.addI;
  c.C[(size_t)i * c.ldc + j] = s;
  if (c.out2) c.out2[(size_t)i * c.N + j] = s * c.sc2 + ((i == j) ? c.dg2 : 0.0f);
}

__global__ __launch_bounds__(256)
void scaleshift_k(const float* in, float* out, int n, float sc, float dg) {
  size_t idx = (size_t)blockIdx.x * 256 + threadIdx.x;
  if (idx >= (size_t)n * n) return;
  int i = (int)(idx / n), j = (int)(idx % n);
  out[idx] = in[idx] * sc + ((i == j) ? dg : 0.0f);
}

__global__ __launch_bounds__(256)
void symscale_k(const float* in, float* out, int n, float sc, float dg) {
  size_t idx = (size_t)blockIdx.x * 256 + threadIdx.x;
  if (idx >= (size_t)n * n) return;
  int i = (int)(idx / n), j = (int)(idx % n);
  out[idx] = 0.5f * (in[idx] + in[(size_t)j * n + i]) * sc + ((i == j) ? dg : 0.0f);
}

// ---------------------------------------------------------------------------
__global__ __launch_bounds__(256)
void colmean_part_k(const float* x, double* part) {
  int col = blockIdx.x * 256 + threadIdx.x;
  int rs = blockIdx.y;
  double acc = 0.0;
  for (int r = rs * 512; r < (rs + 1) * 512; ++r)
    acc += (double)x[(size_t)r * D_N + col];
  part[(size_t)rs * D_N + col] = acc;
}

__global__ __launch_bounds__(256)
void colmean_comb_k(const double* part, float* m) {
  int col = blockIdx.x * 256 + threadIdx.x;
  double acc = 0.0;
  for (int rs = 0; rs < 16; ++rs) acc += part[(size_t)rs * D_N + col];
  m[col] = (float)(acc / (double)B_N);
}

__global__ void inits_k(float* S, int n, unsigned seed) {
  int i = blockIdx.x * 256 + threadIdx.x;
  if (i < n) S[i] = hashf((unsigned)i * 2654435761u + seed);
}

// ---------------------------------------------------------------------------
// Blocked LDL^T (NB=16, register panel via __shfl in wave 0; GEMM-style
// rank-16 trailing update). 512 threads. (validated v7/v8)
// ---------------------------------------------------------------------------
__device__ __forceinline__
void ldl128(float (&A)[128][129], float* Dsh, int tid) {
  for (int b = 0; b < 8; ++b) {
    const int o = b * 16;
    if (tid < 64) {
      const int lane = tid;
      float ra[16], rb[16], Dv[16];
#pragma unroll
      for (int q = 0; q < 16; ++q) {
        ra[q] = A[lane][o + q];
        rb[q] = A[lane + 64][o + q];
      }
#pragma unroll
      for (int jj = 0; jj < 16; ++jj) {
        const int c = o + jj;
        float pj = (c < 64) ? __shfl(ra[jj], c) : __shfl(rb[jj], c - 64);
        pj = fmaxf(pj, 1e-30f);
        Dv[jj] = pj;
        const float rdj = 1.0f / pj;
        const float ua = ra[jj] * rdj;
        const float ub = rb[jj] * rdj;
#pragma unroll
        for (int t = jj + 1; t < 16; ++t) {
          const int rt = o + t;
          float atj = (rt < 64) ? __shfl(ra[jj], rt) : __shfl(rb[jj], rt - 64);
          ra[t] -= ua * atj;
          rb[t] -= ub * atj;
        }
        ra[jj] = ua; rb[jj] = ub;
      }
#pragma unroll
      for (int q = 0; q < 16; ++q) {
        A[lane][o + q] = ra[q];
        A[lane + 64][o + q] = rb[q];
      }
#pragma unroll
      for (int q = 0; q < 16; ++q)
        if (lane == q) Dsh[o + q] = Dv[q];
    }
    __syncthreads();
    if (o + 16 < 128) {
      const int tx = tid & 15, ty = tid >> 4;
      for (int i = o + 16 + ty; i < 128; i += 32) {
        float w[16];
#pragma unroll
        for (int q = 0; q < 16; ++q) w[q] = A[i][o + q] * Dsh[o + q];
        for (int t = o + 16 + tx; t <= i; t += 16) {
          float s = A[i][t];
#pragma unroll
          for (int q = 0; q < 16; ++q) s -= w[q] * A[t][o + q];
          A[i][t] = s;
        }
      }
    }
    __syncthreads();
  }
}

// chol + triangular inverse. Y is a raw 4160+-float scratch (pitch 65).
__device__ __forceinline__
void cholinv128(float (&A)[128][129], float (&Bm)[128][129],
                float* Y, float* Dsh, float* sqv, int tid) {
  for (int idx = tid; idx < 128 * 129; idx += 512)
    (&Bm[0][0])[idx] = 0.0f;
  __syncthreads();
  ldl128(A, Dsh, tid);
  if (tid < 128) sqv[tid] = sqrtf(Dsh[tid]);
  __syncthreads();
  for (int idx = tid; idx < 128 * 128; idx += 512) {
    int i = idx >> 7, j = idx & 127;
    if (j <= i) A[i][j] *= sqv[j];
  }
  __syncthreads();
  if (tid < 128) {
    const int ob = (tid >> 6) * 64;
    const int c = tid & 63;
    for (int i = c; i < 64; ++i) {
      float s = (i == c) ? 1.0f : 0.0f;
      for (int t = c; t < i; ++t) s -= A[ob + i][ob + t] * Bm[ob + c][ob + t];
      Bm[ob + c][ob + i] = s / A[ob + i][ob + i];
    }
  }
  __syncthreads();
  for (int idx = tid; idx < 64 * 64; idx += 512) {
    int t = idx >> 6, c = idx & 63;
    float s = 0.0f;
    for (int s2 = c; s2 < 64; ++s2) s += A[64 + t][s2] * Bm[c][s2];
    Y[t * 65 + c] = s;
  }
  __syncthreads();
  for (int idx = tid; idx < 64 * 64; idx += 512) {
    int a = idx >> 6, c = idx & 63;
    float s = 0.0f;
    for (int t = 0; t <= a; ++t) s -= Bm[64 + t][64 + a] * Y[t * 65 + c];
    Bm[c][64 + a] = s;
  }
  __syncthreads();
}

// ---------------------------------------------------------------------------
__global__ __launch_bounds__(512)
void chol128_k(const float* Gin, int ldg, float* LinvT, double* logdet, float* Sinv) {
  __shared__ float A[128][129];
  __shared__ float Bm[128][129];
  __shared__ float Y[4160];
  __shared__ float Dsh[128], sqv[128];
  const int tid = threadIdx.x;
  for (int idx = tid; idx < 128 * 128; idx += 512)
    A[idx >> 7][idx & 127] = Gin[(size_t)(idx >> 7) * ldg + (idx & 127)];
  __syncthreads();
  cholinv128(A, Bm, Y, Dsh, sqv, tid);
  if (logdet && tid == 0) {
    double s = 0.0;
    for (int j = 0; j < 128; ++j) s += log((double)Dsh[j]);
    *logdet = s;
  }
  if (LinvT)
    for (int idx = tid; idx < 128 * 128; idx += 512)
      LinvT[idx] = Bm[idx >> 7][idx & 127];
  if (Sinv)
    for (int idx = tid; idx < 128 * 128; idx += 512) {
      int i = idx >> 7, j = idx & 127;
      int t0 = (i > j) ? i : j;
      float s = 0.0f;
      for (int t = t0; t < 128; ++t) s += Bm[i][t] * Bm[j][t];
      Sinv[idx] = s;
    }
}

// ---------------------------------------------------------------------------
// qrf_k v2: fused blocked CholQR-256 with LDS-staged matmul phases.
//   Rinv = [[L11^-T, -L11^-T L21^T L22^-T], [0, L22^-T]]
// SY (4224 floats) overlays cholinv's Y scratch AND the per-phase staging
// buffers (row-chunk pitch 33, Pg-chunk pitch 132). 512 threads, one WG.
// ---------------------------------------------------------------------------
__global__ __launch_bounds__(512)
void qrf_k(const float* G, int ldg, float* Rinv, float* Pg) {
  __shared__ float A[128][129];
  __shared__ float Bm[128][129];
  __shared__ float SY[4224];
  __shared__ float Dsh[128], sqv[128];
  const int tid = threadIdx.x;
  const int jl = tid & 31;        // col j(c) = jl + 32c, c<4
  const int il = tid >> 5;        // row i(r) = il + 16r, r<8
  // phase 1: chol+inv of G11 -> Bm = Li11T
  for (int idx = tid; idx < 128 * 128; idx += 512)
    A[idx >> 7][idx & 127] = G[(size_t)(idx >> 7) * ldg + (idx & 127)];
  __syncthreads();
  cholinv128(A, Bm, SY, Dsh, sqv, tid);
  // Rinv TL = Bm; BL = 0
  for (int idx = tid; idx < 128 * 128; idx += 512) {
    int k = idx >> 7, j = idx & 127;
    Rinv[(size_t)k * 256 + j] = Bm[k][j];
    Rinv[(size_t)(128 + k) * 256 + j] = 0.0f;
  }
  __syncthreads();
  // phase 2: L21[i][j] = sum_t G21[i][t] * Bm[t][j]   (G21 staged in SY)
  {
    float acc[8][4] = {};
    for (int t0 = 0; t0 < 128; t0 += 32) {
      for (int q = tid; q < 128 * 8; q += 512) {
        int i = q >> 3, c4 = q & 7;
        *(float4*)&SY[i * 33 + c4 * 4] =
            *(const float4*)&G[(size_t)(128 + i) * ldg + t0 + c4 * 4];
      }
      __syncthreads();
      for (int t = 0; t < 32; ++t) {
        float bv[4];
#pragma unroll
        for (int c = 0; c < 4; ++c) bv[c] = Bm[t0 + t][jl + 32 * c];
#pragma unroll
        for (int r = 0; r < 8; ++r) {
          float gv = SY[(il + 16 * r) * 33 + t];
#pragma unroll
          for (int c = 0; c < 4; ++c) acc[r][c] += gv * bv[c];
        }
      }
      __syncthreads();
    }
#pragma unroll
    for (int r = 0; r < 8; ++r)
#pragma unroll
      for (int c = 0; c < 4; ++c) {
        int i = il + 16 * r, j = jl + 32 * c;
        A[i][j] = acc[r][c];
        Pg[(size_t)i * 128 + j] = acc[r][c];
      }
  }
  __syncthreads();
  // phase 3: Schur = G22 - L21 L21^T  (A holds L21; all-LDS; write into A)
  {
    float acc[8][4] = {};
    for (int t = 0; t < 128; ++t) {
      float bv[4];
#pragma unroll
      for (int c = 0; c < 4; ++c) bv[c] = A[jl + 32 * c][t];
#pragma unroll
      for (int r = 0; r < 8; ++r) {
        float av = A[il + 16 * r][t];
#pragma unroll
        for (int c = 0; c < 4; ++c) acc[r][c] += av * bv[c];
      }
    }
    __syncthreads();
#pragma unroll
    for (int r = 0; r < 8; ++r)
#pragma unroll
      for (int c = 0; c < 4; ++c) {
        int i = il + 16 * r, j = jl + 32 * c;
        A[i][j] = G[(size_t)(128 + i) * ldg + 128 + j] - acc[r][c];
      }
  }
  __syncthreads();
  // phase 4: chol+inv of Schur -> Bm = Li22T; Rinv BR
  cholinv128(A, Bm, SY, Dsh, sqv, tid);
  for (int idx = tid; idx < 128 * 128; idx += 512) {
    int k = idx >> 7, j = idx & 127;
    Rinv[(size_t)(128 + k) * 256 + 128 + j] = Bm[k][j];
  }
  __syncthreads();
  // phase 5: M1[t][j] = sum_s Pg[s][t] * Bm[s][j]   (Pg staged in SY) -> A
  {
    float acc[8][4] = {};
    for (int s0 = 0; s0 < 128; s0 += 32) {
      for (int q = tid; q < 32 * 32; q += 512) {
        int sr = q >> 5, c4 = q & 31;
        *(float4*)&SY[sr * 132 + c4 * 4] =
            *(const float4*)&Pg[(size_t)(s0 + sr) * 128 + c4 * 4];
      }
      __syncthreads();
      for (int s = 0; s < 32; ++s) {
        float bv[4];
#pragma unroll
        for (int c = 0; c < 4; ++c) bv[c] = Bm[s0 + s][jl + 32 * c];
#pragma unroll
        for (int r = 0; r < 8; ++r) {
          float pv = SY[s * 132 + il + 16 * r];
#pragma unroll
          for (int c = 0; c < 4; ++c) acc[r][c] += pv * bv[c];
        }
      }
      __syncthreads();
    }
#pragma unroll
    for (int r = 0; r < 8; ++r)
#pragma unroll
      for (int c = 0; c < 4; ++c)
        A[il + 16 * r][jl + 32 * c] = acc[r][c];
  }
  __syncthreads();
  // phase 6: TR[k][j] = -sum_t RinvTL[k][t] * M1[t][j]  (RinvTL staged)
  {
    float acc[8][4] = {};
    for (int t0 = 0; t0 < 128; t0 += 32) {
      for (int q = tid; q < 128 * 8; q += 512) {
        int k = q >> 3, c4 = q & 7;
        *(float4*)&SY[k * 33 + c4 * 4] =
            *(const float4*)&Rinv[(size_t)k * 256 + t0 + c4 * 4];
      }
      __syncthreads();
      for (int t = 0; t < 32; ++t) {
        float bv[4];
#pragma unroll
        for (int c = 0; c < 4; ++c) bv[c] = A[t0 + t][jl + 32 * c];
#pragma unroll
        for (int r = 0; r < 8; ++r) {
          float rv = SY[(il + 16 * r) * 33 + t];
#pragma unroll
          for (int c = 0; c < 4; ++c) acc[r][c] += rv * bv[c];
        }
      }
      __syncthreads();
    }
#pragma unroll
    for (int r = 0; r < 8; ++r)
#pragma unroll
      for (int c = 0; c < 4; ++c)
        Rinv[(size_t)(il + 16 * r) * 256 + 128 + jl + 32 * c] = -acc[r][c];
  }
}

__global__ __launch_bounds__(128)
void mw_k(const float* m, const float* W, float* mW) {
  int j = threadIdx.x;
  double acc = 0.0;
  for (int c = 0; c < D_N; ++c) acc += (double)m[c] * (double)W[(size_t)c * K_N + j];
  mW[j] = (float)acc;
}

// ---------------------------------------------------------------------------
__global__ __launch_bounds__(256)
void count_sort_k(const int* lab, int* perm, int* counts, int* offs) {
  __shared__ int cnt[NLAB][256];
  __shared__ int labOff[NLAB + 1];
  const int tid = threadIdx.x;
  int lc[NLAB];
#pragma unroll
  for (int l = 0; l < NLAB; ++l) lc[l] = 0;
  for (int r = tid * 32; r < tid * 32 + 32; ++r) {
    int l = lab[r]; l = (l < 0) ? 0 : (l > 9 ? 9 : l);
    lc[l]++;
  }
#pragma unroll
  for (int l = 0; l < NLAB; ++l) cnt[l][tid] = lc[l];
  __syncthreads();
  if (tid < NLAB) {
    int run = 0;
    for (int i = 0; i < 256; ++i) { int v = cnt[tid][i]; cnt[tid][i] = run; run += v; }
    counts[tid] = run;
  }
  __syncthreads();
  if (tid == 0) {
    int run = 0;
    for (int l = 0; l < NLAB; ++l) { labOff[l] = run; run += counts[l]; }
    labOff[NLAB] = run;
    for (int l = 0; l <= NLAB; ++l) offs[l] = labOff[l];
  }
  __syncthreads();
  int lc2[NLAB];
#pragma unroll
  for (int l = 0; l < NLAB; ++l) lc2[l] = 0;
  for (int r = tid * 32; r < tid * 32 + 32; ++r) {
    int l = lab[r]; l = (l < 0) ? 0 : (l > 9 ? 9 : l);
    int pos = labOff[l] + cnt[l][tid] + lc2[l];
    lc2[l]++;
    perm[pos] = r;
  }
}

__global__ __launch_bounds__(256)
void gather_k(const float* z, const int* perm, float* zs) {
  int g = blockIdx.x * 256 + threadIdx.x;
  int row = g >> 5, q = g & 31;
  const float4* zf = (const float4*)z;
  float4* of = (float4*)zs;
  of[(size_t)row * 32 + q] = zf[(size_t)perm[row] * 32 + q];
}

__global__ __launch_bounds__(128)
void labstat_part_k(const float* zs, const int* offs, double* part) {
  int l = blockIdx.x >> 3, s = blockIdx.x & 7;
  int j = threadIdx.x;
  int r0, r1;
  if (l < NLAB) {
    int st = offs[l], en = offs[l + 1], len = en - st;
    r0 = st + (int)(((long long)len * s) >> 3);
    r1 = st + (int)(((long long)len * (s + 1)) >> 3);
  } else {
    r0 = s * 1024; r1 = r0 + 1024;
  }
  double acc = 0.0;
  for (int r = r0; r < r1; ++r) acc += (double)zs[(size_t)r * K_N + j];
  part[((size_t)l * 8 + s) * K_N + j] = acc;
}

__global__ __launch_bounds__(128)
void labstat_comb_k(const double* part, float* sum_mu, float* muT) {
  int j = threadIdx.x;
  for (int l = 0; l < NLAB; ++l) {
    double a = 0.0;
    for (int s = 0; s < 8; ++s) a += part[((size_t)l * 8 + s) * K_N + j];
    sum_mu[l * K_N + j] = (float)a;
  }
  double t = 0.0;
  for (int s = 0; s < 8; ++s) t += part[((size_t)NLAB * 8 + s) * K_N + j];
  muT[j] = (float)(t / (double)B_N);
}

__global__ __launch_bounds__(256)
void sigsum_k(const float* zs, const int* offs, const float* muT, float* SigS) {
  int l = blockIdx.x >> 2, t = blockIdx.x & 3;
  int i0 = (t >> 1) * 64, j0 = (t & 1) * 64;
  __shared__ float Zi[32][66], Zj[32][66];
  __shared__ float muL[128];
  int tid = threadIdx.x, tx = tid & 15, ty = tid >> 4;
  if (tid < 128) muL[tid] = muT[tid];
  __syncthreads();
  int start = offs[l], end = offs[l + 1];
  float acc[4][4] = {};
  for (int base = start; base < end; base += 32) {
#pragma unroll
    for (int p = 0; p < 8; ++p) {
      int idx = tid + p * 256;
      int rr = idx >> 6, cc = idx & 63;
      int r = base + rr;
      float vi = 0.0f, vj = 0.0f;
      if (r < end) {
        vi = zs[(size_t)r * K_N + i0 + cc] - muL[i0 + cc];
        vj = zs[(size_t)r * K_N + j0 + cc] - muL[j0 + cc];
      }
      Zi[rr][cc] = vi; Zj[rr][cc] = vj;
    }
    __syncthreads();
    for (int rr = 0; rr < 32; ++rr) {
      float ra[4], rb[4];
#pragma unroll
      for (int r = 0; r < 4; ++r) ra[r] = Zi[rr][ty * 4 + r];
#pragma unroll
      for (int c = 0; c < 4; ++c) rb[c] = Zj[rr][tx * 4 + c];
#pragma unroll
      for (int r = 0; r < 4; ++r)
#pragma unroll
        for (int c = 0; c < 4; ++c) acc[r][c] += ra[r] * rb[c];
    }
    __syncthreads();
  }
#pragma unroll
  for (int r = 0; r < 4; ++r)
#pragma unroll
    for (int c = 0; c < 4; ++c)
      SigS[((size_t)l * K_N + i0 + ty * 4 + r) * K_N + j0 + tx * 4 + c] = acc[r][c];
}

__global__ __launch_bounds__(256)
void sigt_comb_k(const float* SigS, float* SigT) {
  int idx = blockIdx.x * 256 + threadIdx.x;
  int i = idx >> 7, j = idx & 127;
  double s = 0.0;
  for (int l = 0; l < NLAB; ++l) s += (double)SigS[(size_t)l * 16384 + idx];
  SigT[idx] = (float)(s / (double)B_N) + ((i == j) ? 1.0f : 0.0f);
}

// ---------------------------------------------------------------------------
__global__ __launch_bounds__(512)
void perlabel_k(const float* SigS, const float* Sinv, const float* mu,
                const float* sum_mu, const int* counts, const double* logdet_t,
                double* klout, int* present) {
  int l = blockIdx.x, tid = threadIdx.x;
  __shared__ float Amat[128][129];
  __shared__ double red[512];
  __shared__ float dv[128];
  __shared__ float Dsh[128];
  int cnt = counts[l];
  float sc = (cnt > 0) ? (float)cnt : 1.0f;
  for (int idx = tid; idx < 128 * 128; idx += 512) {
    int i = idx >> 7, j = idx & 127;
    Amat[i][j] = SigS[((size_t)l * K_N + i) * K_N + j] / sc + ((i == j) ? 1.0f : 0.0f);
  }
  if (tid < 128) dv[tid] = mu[tid] - sum_mu[l * K_N + tid] / sc;
  __syncthreads();
  double tr = 0.0, mh = 0.0;
  for (int idx = tid; idx < 128 * 128; idx += 512) {
    int i = idx >> 7, j = idx & 127;
    double sv = (double)Sinv[idx];
    tr += sv * (double)Amat[i][j];
    mh += sv * (double)dv[i] * (double)dv[j];
  }
  red[tid] = tr; __syncthreads();
  for (int off = 256; off > 0; off >>= 1) { if (tid < off) red[tid] += red[tid + off]; __syncthreads(); }
  double trv = red[0]; __syncthreads();
  red[tid] = mh; __syncthreads();
  for (int off = 256; off > 0; off >>= 1) { if (tid < off) red[tid] += red[tid + off]; __syncthreads(); }
  double mhv = red[0]; __syncthreads();
  ldl128(Amat, Dsh, tid);
  if (tid == 0) {
    double ld = 0.0;
    for (int j = 0; j < 128; ++j) ld += log((double)Dsh[j]);
    klout[l] = 0.5 * (trv + mhv - 128.0 + logdet_t[0] - ld);
    present[l] = (cnt > 0) ? 1 : 0;
  }
}

__global__ void finalize_k(const double* kl, const int* present, float* out) {
  if (threadIdx.x == 0 && blockIdx.x == 0) {
    double s = 0.0; int np = 0;
    for (int l = 0; l < NLAB; ++l)
      if (present[l]) { s += kl[l]; np++; }
    out[0] = (float)((np > 0) ? s / ((double)np * (double)B_N) : 0.0);
  }
}

// ===========================================================================
// Host side
// ===========================================================================
static inline GArgs mkg(const float* A, int lda, const float* B, int ldb,
                        float* C, int ldc, int K, float alpha) {
  GArgs g{};
  g.A = A; g.B = B; g.C = C; g.lda = lda; g.ldb = ldb; g.ldc = ldc;
  g.K = K; g.alpha = alpha;
  return g;
}

static inline void run_g(hipStream_t st, bool akm, bool bt, GArgs g,
                         int M, int N, int ks, float* Ppart) {
  if (ks > 1) {
    g.Cp = Ppart; g.mn = (size_t)M * N; g.pn = N;
    dim3 grid(M / 64, N / 64, ks);
    if (akm)     hipLaunchKernelGGL((gemm_k<true, false>),  grid, dim3(256), 0, st, g);
    else if (bt) hipLaunchKernelGGL((gemm_k<false, true>),  grid, dim3(256), 0, st, g);
    else         hipLaunchKernelGGL((gemm_k<false, false>), grid, dim3(256), 0, st, g);
    CArgs c{Ppart, g.C, (size_t)M * N, N, g.ldc, ks,
            g.C1, g.b1, g.ldc1, g.C2, g.b2, g.ldc2,
            g.r1u, g.r1v, g.r1c, g.radd, g.raddc, g.addI,
            g.out2, g.sc2, g.dg2};
    hipLaunchKernelGGL(combine_k, dim3((unsigned)(((size_t)M * N + 255) / 256)),
                       dim3(256), 0, st, c);
  } else {
    dim3 grid(M / 64, N / 64);
    if (akm)     hipLaunchKernelGGL((gemm_k<true, false>),  grid, dim3(256), 0, st, g);
    else if (bt) hipLaunchKernelGGL((gemm_k<false, true>),  grid, dim3(256), 0, st, g);
    else         hipLaunchKernelGGL((gemm_k<false, false>), grid, dim3(256), 0, st, g);
  }
}

extern "C" void kernel_launch(void* const* d_in, const int* in_sizes, int n_in,
                              void* d_out, int out_size, void* d_ws, size_t ws_size,
                              hipStream_t stream) {
  const float* x = (const float*)d_in[0];
  const int* lab = (const int*)d_in[1];
  float* out = (float*)d_out;

  size_t off = 0;
  auto alloc = [&](size_t nbytes) -> void* {
    void* r = (void*)((char*)d_ws + off);
    off += ((nbytes + 255) / 256) * 256;
    return r;
  };
  float*  m     = (float*) alloc(D_N * 4);
  float*  Cn    = (float*) alloc((size_t)D_N * D_N * 4);
  float*  At    = (float*) alloc((size_t)D_N * D_N * 4);  // Atilde -> T4 -> zs
  float*  T2    = (float*) alloc((size_t)D_N * D_N * 4);  // T2 -> z
  float*  Fo    = (float*) alloc((size_t)D_N * D_N * 4);  // outer filter T6
  float*  SA    = (float*) alloc((size_t)D_N * M_N * 4);
  float*  SB    = (float*) alloc((size_t)D_N * M_N * 4);
  float*  SC    = (float*) alloc((size_t)D_N * M_N * 4);
  float*  G256  = (float*) alloc((size_t)M_N * M_N * 4);  // -> F12i
  float*  Tm    = (float*) alloc((size_t)M_N * M_N * 4);
  float*  Rb    = (float*) alloc((size_t)M_N * M_N * 4);  // Rinv from qrf
  float*  Pg2   = (float*) alloc((size_t)K_N * K_N * 4);  // qrf scratch (L21)
  float*  Tt    = (float*) alloc((size_t)M_N * M_N * 4);
  float*  T2i   = (float*) alloc((size_t)M_N * M_N * 4);
  float*  T4i   = (float*) alloc((size_t)M_N * M_N * 4);
  float*  F6i   = (float*) alloc((size_t)M_N * M_N * 4);
  float*  VA    = (float*) alloc((size_t)M_N * K_N * 4);
  float*  VB    = (float*) alloc((size_t)M_N * K_N * 4);
  float*  G128  = (float*) alloc((size_t)K_N * K_N * 4);
  float*  Li128 = (float*) alloc((size_t)K_N * K_N * 4);
  float*  Wa    = (float*) alloc((size_t)D_N * K_N * 4);
  float*  Wb    = (float*) alloc((size_t)D_N * K_N * 4);
  float*  mW    = (float*) alloc(K_N * 4);
  double* partM = (double*)alloc((size_t)16 * D_N * 8);
  double* partL = (double*)alloc((size_t)11 * 8 * K_N * 8);
  float*  sumMu = (float*) alloc(NLAB * K_N * 4);
  float*  muT   = (float*) alloc(K_N * 4);
  float*  SigT  = (float*) alloc((size_t)K_N * K_N * 4);
  float*  Sinv  = (float*) alloc((size_t)K_N * K_N * 4);
  float*  SigS  = (float*) alloc((size_t)NLAB * K_N * K_N * 4);
  double* logdet_t = (double*)alloc(16);
  double* klv      = (double*)alloc(NLAB * 8);
  int*    counts = (int*)alloc(16 * 4);
  int*    offs   = (int*)alloc(16 * 4);
  int*    present= (int*)alloc(16 * 4);
  int*    perm   = (int*)alloc(B_N * 4);
  float*  T4   = At;    // alias: At dead once T2 exists
  float*  F12i = G256;  // alias: G256 dead after outer segs
  float*  zs   = At;    // alias: T4 dead after Fo; zs written step 9
  float*  z    = T2;    // alias: T2 dead after Fo
  size_t rem = (ws_size > off) ? (ws_size - off) : 0;
  int KS = 1, KSC = 1;
  size_t pbytes = 0;
  if (rem >= (size_t)33 * 1024 * 1024)      { KSC = 8; KS = 4; pbytes = (size_t)32 * 1024 * 1024; }
  else if (rem >= (size_t)17 * 1024 * 1024) { KSC = 4; KS = 4; pbytes = (size_t)16 * 1024 * 1024; }
  else if (rem >= (size_t)9 * 1024 * 1024)  { KSC = 2; KS = 2; pbytes = (size_t)8 * 1024 * 1024; }
  float* Ppart = pbytes ? (float*)alloc(pbytes) : nullptr;
  const int gks = (KS >= 4) ? 8 : KS;   // split factor for small-output Grams
  (void)in_sizes; (void)n_in; (void)out_size;

  // 1) column means; Cn = x^T x / B - m m^T ; At = 1.6*Cn - I (fused)
  hipLaunchKernelGGL(colmean_part_k, dim3(4, 16), dim3(256), 0, stream, x, partM);
  hipLaunchKernelGGL(colmean_comb_k, dim3(4), dim3(256), 0, stream, partM, m);
  {
    GArgs g = mkg(x, D_N, x, D_N, Cn, D_N, B_N, 1.0f / (float)B_N);
    g.r1u = m; g.r1v = m; g.r1c = -1.0f;
    if (KSC > 1) { g.out2 = At; g.sc2 = 1.6f; g.dg2 = -1.0f; }
    run_g(stream, true, false, g, D_N, D_N, KSC, Ppart);
    if (KSC == 1)
      hipLaunchKernelGGL(scaleshift_k, dim3((D_N * D_N + 255) / 256), dim3(256),
                         0, stream, Cn, At, D_N, 1.6f, -1.0f);
  }

  // 2) Outer filter Fo = T6(At) = 2*T2*T4 - T2, band [0,1.25] (c=d=0.625)
  {
    GArgs g = mkg(At, D_N, At, D_N, T2, D_N, D_N, 2.0f);  // T2 = 2 At^2 - I
    g.addI = -1.0f;
    run_g(stream, true, false, g, D_N, D_N, KS, Ppart);
    g = mkg(T2, D_N, T2, D_N, T4, D_N, D_N, 2.0f);        // T4 = 2 T2^2 - I
    g.addI = -1.0f;
    run_g(stream, true, false, g, D_N, D_N, KS, Ppart);
    g = mkg(T2, D_N, T4, D_N, Fo, D_N, D_N, 2.0f);        // T6 = 2 T2 T4 - T2
    g.C1 = T2; g.b1 = -1.0f; g.ldc1 = D_N;
    run_g(stream, true, false, g, D_N, D_N, KS, Ppart);
  }

  // Fused blocked CholQR-256: Gram -> qrf (Rinv) -> Snew = S * Rinv
  auto qr256 = [&](float* S, float* Snew) {
    GArgs g = mkg(S, M_N, S, M_N, G256, M_N, D_N, 1.0f);
    run_g(stream, true, false, g, M_N, M_N, gks, Ppart);
    hipLaunchKernelGGL(qrf_k, dim3(1), dim3(512), 0, stream, G256, M_N, Rb, Pg2);
    g = mkg(S, M_N, Rb, M_N, Snew, M_N, M_N, 1.0f);
    run_g(stream, false, false, g, D_N, M_N, KS, Ppart);
  };

  // 3) Outer: 2 segments of {S <- Fo @ S ; CholQR-256}
  hipLaunchKernelGGL(inits_k, dim3((D_N * M_N + 255) / 256), dim3(256), 0, stream,
                     SA, D_N * M_N, 12345u);
  float* Scur = SA; float* t1 = SB; float* t2 = SC;
  for (int seg = 0; seg < 2; ++seg) {
    GArgs g = mkg(Fo, D_N, Scur, M_N, t1, M_N, D_N, 1.0f);
    run_g(stream, true, false, g, D_N, M_N, KS, Ppart);
    qr256(t1, t2);
    float* t = Scur; Scur = t2; t2 = t;
  }

  // 4) T = S^T (Cn S)
  {
    GArgs g = mkg(Cn, D_N, Scur, M_N, t1, M_N, D_N, 1.0f);
    run_g(stream, true, false, g, D_N, M_N, KS, Ppart);
    g = mkg(Scur, M_N, t1, M_N, Tm, M_N, D_N, 1.0f);
    run_g(stream, true, false, g, M_N, M_N, gks, Ppart);
  }

  // 5) Inner filter F12 = T12(Tt) = 2*T6(Tt)^2 - I, band [0,1.27] (c=d=0.635)
  hipLaunchKernelGGL(symscale_k, dim3((M_N * M_N + 255) / 256), dim3(256), 0,
                     stream, Tm, Tt, M_N, 1.0f / 0.635f, -1.0f);
  {
    GArgs g = mkg(Tt, M_N, Tt, M_N, T2i, M_N, M_N, 2.0f);
    g.addI = -1.0f;
    run_g(stream, true, false, g, M_N, M_N, 1, nullptr);
    g = mkg(T2i, M_N, T2i, M_N, T4i, M_N, M_N, 2.0f);
    g.addI = -1.0f;
    run_g(stream, true, false, g, M_N, M_N, 1, nullptr);
    g = mkg(T2i, M_N, T4i, M_N, F6i, M_N, M_N, 2.0f);
    g.C1 = T2i; g.b1 = -1.0f; g.ldc1 = M_N;
    run_g(stream, true, false, g, M_N, M_N, 1, nullptr);
    g = mkg(F6i, M_N, F6i, M_N, F12i, M_N, M_N, 2.0f);
    g.addI = -1.0f;
    run_g(stream, true, false, g, M_N, M_N, 1, nullptr);
  }

  // 6) Inner: 1 segment {V <- F12 @ V ; CholQR-128}
  hipLaunchKernelGGL(inits_k, dim3((M_N * K_N + 255) / 256), dim3(256), 0, stream,
                     VA, M_N * K_N, 777u);
  {
    GArgs g = mkg(F12i, M_N, VA, K_N, VB, K_N, M_N, 1.0f);
    run_g(stream, true, false, g, M_N, K_N, 1, nullptr);
    g = mkg(VB, K_N, VB, K_N, G128, K_N, M_N, 1.0f);
    run_g(stream, true, false, g, K_N, K_N, 1, nullptr);
    hipLaunchKernelGGL(chol128_k, dim3(1), dim3(512), 0, stream,
                       G128, K_N, Li128, (double*)nullptr, (float*)nullptr);
    g = mkg(VB, K_N, Li128, K_N, VA, K_N, K_N, 1.0f);
    run_g(stream, false, false, g, M_N, K_N, 1, nullptr);
  }

  // 7) W = S*V, exact CholQR-128 on W (CholQR2 pattern)
  {
    GArgs g = mkg(Scur, M_N, VA, K_N, Wa, K_N, M_N, 1.0f);
    run_g(stream, false, false, g, D_N, K_N, 1, nullptr);
    g = mkg(Wa, K_N, Wa, K_N, G128, K_N, D_N, 1.0f);
    run_g(stream, true, false, g, K_N, K_N, gks, Ppart);
    hipLaunchKernelGGL(chol128_k, dim3(1), dim3(512), 0, stream,
                       G128, K_N, Li128, (double*)nullptr, (float*)nullptr);
    g = mkg(Wa, K_N, Li128, K_N, Wb, K_N, K_N, 1.0f);
    run_g(stream, false, false, g, D_N, K_N, 1, nullptr);
  }

  // 8) z = x W - 1 (m^T W)
  hipLaunchKernelGGL(mw_k, dim3(1), dim3(128), 0, stream, m, Wb, mW);
  {
    GArgs g = mkg(x, D_N, Wb, K_N, z, K_N, D_N, 1.0f);
    g.radd = mW; g.raddc = -1.0f;
    run_g(stream, false, false, g, B_N, K_N, KS, Ppart);
  }

  // 9) sort rows by label; gather into zs
  hipLaunchKernelGGL(count_sort_k, dim3(1), dim3(256), 0, stream,
                     lab, perm, counts, offs);
  hipLaunchKernelGGL(gather_k, dim3(B_N * 32 / 256), dim3(256), 0, stream,
                     z, perm, zs);

  // 10) label and global column sums
  hipLaunchKernelGGL(labstat_part_k, dim3(11 * 8), dim3(128), 0, stream,
                     zs, offs, partL);
  hipLaunchKernelGGL(labstat_comb_k, dim3(1), dim3(128), 0, stream,
                     partL, sumMu, muT);

  // 11) per-label Sigma sums; SigT; Sinv + logdet
  hipLaunchKernelGGL(sigsum_k, dim3(NLAB * 4), dim3(256), 0, stream,
                     zs, offs, muT, SigS);
  hipLaunchKernelGGL(sigt_comb_k, dim3(64), dim3(256), 0, stream, SigS, SigT);
  hipLaunchKernelGGL(chol128_k, dim3(1), dim3(512), 0, stream,
                     SigT, K_N, (float*)nullptr, logdet_t, Sinv);

  // 12) per-label KL, reduce
  hipLaunchKernelGGL(perlabel_k, dim3(NLAB), dim3(512), 0, stream,
                     SigS, Sinv, muT, sumMu, counts, logdet_t, klv, present);
  hipLaunchKernelGGL(finalize_k, dim3(1), dim3(64), 0, stream, klv, present, out);
}

// Round 10
// 2285.810 us; speedup vs baseline: 1.1086x; 1.0876x over previous
//
#include <hip/hip_runtime.h>
#include <hip/hip_bf16.h>
#include <math.h>

// ============================================================================
// GMMLoss2_pca v10: blocked-recursive triangular inverse (kills the 2016-step
// serial chains in cholinv128), 128x128-tile GEMM for the four 1024^3
// products. Pipeline otherwise = v9.
// ============================================================================

#define B_N 8192
#define D_N 1024
#define K_N 128
#define M_N 256
#define NLAB 10

__device__ __forceinline__ float hashf(unsigned x) {
  x ^= x >> 16; x *= 0x7feb352du; x ^= x >> 15; x *= 0x846ca68bu; x ^= x >> 16;
  return (float)(x >> 8) * (1.0f / 16777216.0f) - 0.5f;
}

// ---------------------------------------------------------------------------
// Tiled f32 GEMM, 64x64 tile (validated v4-v9). Used for all non-1024^3 GEMMs.
// ---------------------------------------------------------------------------
struct GArgs {
  const float* A; const float* B; float* C;
  int lda, ldb, ldc, K;
  float alpha;
  const float* C1; float b1; int ldc1;
  const float* C2; float b2; int ldc2;
  const float* r1u; const float* r1v; float r1c;
  const float* radd; float raddc;
  float addI;
  float* Cp; size_t mn; int pn;      // partial-mode
  float* out2; float sc2, dg2;       // second output (combine only)
};

template <bool AKM, bool BT>
__global__ __launch_bounds__(256)
void gemm_k(GArgs g) {
  __shared__ __align__(16) float AsRaw[2304]; // AKM: [32][68]; !AKM: [64][36]
  __shared__ __align__(16) float Bs[2176];    // [32][68]
  const int tid = threadIdx.x;
  const int tx = tid & 15, ty = tid >> 4;
  const int i0 = blockIdx.x * 64, j0 = blockIdx.y * 64;
  const int ks = gridDim.z;
  const int Kc = g.K / ks;
  const int kbeg = blockIdx.z * Kc, kend = kbeg + Kc;
  float acc[4][4] = {};
  for (int k0 = kbeg; k0 < kend; k0 += 32) {
    if (AKM) {
#pragma unroll
      for (int p = 0; p < 2; ++p) {
        int f4 = tid + p * 256;
        int kk = f4 >> 4, i4 = f4 & 15;
        *(float4*)(AsRaw + kk * 68 + i4 * 4) =
            *(const float4*)(g.A + (size_t)(k0 + kk) * g.lda + i0 + i4 * 4);
      }
    } else {
#pragma unroll
      for (int p = 0; p < 2; ++p) {
        int f4 = tid + p * 256;
        int ii = f4 >> 3, k4 = f4 & 7;
        *(float4*)(AsRaw + ii * 36 + k4 * 4) =
            *(const float4*)(g.A + (size_t)(i0 + ii) * g.lda + k0 + k4 * 4);
      }
    }
    if (BT) {
#pragma unroll
      for (int p = 0; p < 8; ++p) {
        int idx = tid + p * 256;
        int jj = idx >> 5, kk = idx & 31;
        Bs[kk * 68 + jj] = g.B[(size_t)(j0 + jj) * g.ldb + k0 + kk];
      }
    } else {
#pragma unroll
      for (int p = 0; p < 2; ++p) {
        int f4 = tid + p * 256;
        int kk = f4 >> 4, j4 = f4 & 15;
        *(float4*)(Bs + kk * 68 + j4 * 4) =
            *(const float4*)(g.B + (size_t)(k0 + kk) * g.ldb + j0 + j4 * 4);
      }
    }
    __syncthreads();
#pragma unroll 8
    for (int kk = 0; kk < 32; ++kk) {
      float ra[4], rb[4];
      if (AKM) {
        const float4 va = *(const float4*)(AsRaw + kk * 68 + ty * 4);
        ra[0] = va.x; ra[1] = va.y; ra[2] = va.z; ra[3] = va.w;
      } else {
#pragma unroll
        for (int r = 0; r < 4; ++r) ra[r] = AsRaw[(ty * 4 + r) * 36 + kk];
      }
      const float4 vb = *(const float4*)(Bs + kk * 68 + tx * 4);
      rb[0] = vb.x; rb[1] = vb.y; rb[2] = vb.z; rb[3] = vb.w;
#pragma unroll
      for (int r = 0; r < 4; ++r)
#pragma unroll
        for (int c = 0; c < 4; ++c) acc[r][c] += ra[r] * rb[c];
    }
    __syncthreads();
  }
  if (ks > 1) {
    float* dst = g.Cp + (size_t)blockIdx.z * g.mn;
#pragma unroll
    for (int r = 0; r < 4; ++r)
#pragma unroll
      for (int c = 0; c < 4; ++c) {
        int gi = i0 + ty * 4 + r, gj = j0 + tx * 4 + c;
        dst[(size_t)gi * g.pn + gj] = g.alpha * acc[r][c];
      }
  } else {
#pragma unroll
    for (int r = 0; r < 4; ++r)
#pragma unroll
      for (int c = 0; c < 4; ++c) {
        int gi = i0 + ty * 4 + r, gj = j0 + tx * 4 + c;
        float v = g.alpha * acc[r][c];
        if (g.C1) v += g.b1 * g.C1[(size_t)gi * g.ldc1 + gj];
        if (g.C2) v += g.b2 * g.C2[(size_t)gi * g.ldc2 + gj];
        if (g.r1u) v += g.r1c * g.r1u[gi] * g.r1v[gj];
        if (g.radd) v += g.raddc * g.radd[gj];
        if (g.addI != 0.0f && gi == gj) v += g.addI;
        g.C[(size_t)gi * g.ldc + gj] = v;
      }
  }
}

// ---------------------------------------------------------------------------
// 128x128-tile partial GEMM for 1024^3 products: Cp[z] = alpha*sum_k A(k,i)B(k,j)
// over K-slice z. 8x8 per thread, BK=16. Epilogue handled by combine_k.
// ---------------------------------------------------------------------------
__global__ __launch_bounds__(256)
void gemm128p_k(const float* A, const float* B, int lda, int ldb, int K,
                float alpha, float* Cp, int pn, size_t mn) {
  __shared__ __align__(16) float As[16][132];
  __shared__ __align__(16) float Bs[16][132];
  const int tid = threadIdx.x;
  const int tx = tid & 15, ty = tid >> 4;
  const int i0 = blockIdx.x * 128, j0 = blockIdx.y * 128;
  const int Kc = K / gridDim.z;
  const int kbeg = blockIdx.z * Kc, kend = kbeg + Kc;
  float acc[8][8] = {};
  for (int k0 = kbeg; k0 < kend; k0 += 16) {
#pragma unroll
    for (int p = 0; p < 2; ++p) {
      int f4 = tid + p * 256;          // 0..511 : 16 rows x 32 float4
      int kk = f4 >> 5, c4 = f4 & 31;
      *(float4*)&As[kk][c4 * 4] =
          *(const float4*)&A[(size_t)(k0 + kk) * lda + i0 + c4 * 4];
      *(float4*)&Bs[kk][c4 * 4] =
          *(const float4*)&B[(size_t)(k0 + kk) * ldb + j0 + c4 * 4];
    }
    __syncthreads();
#pragma unroll
    for (int kk = 0; kk < 16; ++kk) {
      float ra[8], rb[8];
      *(float4*)&ra[0] = *(const float4*)&As[kk][ty * 8];
      *(float4*)&ra[4] = *(const float4*)&As[kk][ty * 8 + 4];
      *(float4*)&rb[0] = *(const float4*)&Bs[kk][tx * 8];
      *(float4*)&rb[4] = *(const float4*)&Bs[kk][tx * 8 + 4];
#pragma unroll
      for (int r = 0; r < 8; ++r)
#pragma unroll
        for (int c = 0; c < 8; ++c) acc[r][c] += ra[r] * rb[c];
    }
    __syncthreads();
  }
  float* dst = Cp + (size_t)blockIdx.z * mn;
#pragma unroll
  for (int r = 0; r < 8; ++r) {
    int gi = i0 + ty * 8 + r;
#pragma unroll
    for (int c = 0; c < 8; c += 4) {
      float4 v;
      v.x = alpha * acc[r][c];     v.y = alpha * acc[r][c + 1];
      v.z = alpha * acc[r][c + 2]; v.w = alpha * acc[r][c + 3];
      *(float4*)&dst[(size_t)gi * pn + j0 + tx * 8 + c] = v;
    }
  }
}

struct CArgs {
  const float* P; float* C; size_t mn; int N, ldc, ks;
  const float* C1; float b1; int ldc1;
  const float* C2; float b2; int ldc2;
  const float* r1u; const float* r1v; float r1c;
  const float* radd; float raddc;
  float addI;
  float* out2; float sc2, dg2;
};

__global__ __launch_bounds__(256)
void combine_k(CArgs c) {
  size_t idx = (size_t)blockIdx.x * 256 + threadIdx.x;
  if (idx >= c.mn) return;
  int i = (int)(idx / c.N), j = (int)(idx % c.N);
  float s = 0.0f;
  for (int z = 0; z < c.ks; ++z) s += c.P[(size_t)z * c.mn + idx];
  if (c.C1) s += c.b1 * c.C1[(size_t)i * c.ldc1 + j];
  if (c.C2) s += c.b2 * c.C2[(size_t)i * c.ldc2 + j];
  if (c.r1u) s += c.r1c * c.r1u[i] * c.r1v[j];
  if (c.radd) s += c.raddc * c.radd[j];
  if (c.addI != 0.0f && i == j) s += c.addI;
  c.C[(size_t)i * c.ldc + j] = s;
  if (c.out2) c.out2[(size_t)i * c.N + j] = s * c.sc2 + ((i == j) ? c.dg2 : 0.0f);
}

__global__ __launch_bounds__(256)
void scaleshift_k(const float* in, float* out, int n, float sc, float dg) {
  size_t idx = (size_t)blockIdx.x * 256 + threadIdx.x;
  if (idx >= (size_t)n * n) return;
  int i = (int)(idx / n), j = (int)(idx % n);
  out[idx] = in[idx] * sc + ((i == j) ? dg : 0.0f);
}

__global__ __launch_bounds__(256)
void symscale_k(const float* in, float* out, int n, float sc, float dg) {
  size_t idx = (size_t)blockIdx.x * 256 + threadIdx.x;
  if (idx >= (size_t)n * n) return;
  int i = (int)(idx / n), j = (int)(idx % n);
  out[idx] = 0.5f * (in[idx] + in[(size_t)j * n + i]) * sc + ((i == j) ? dg : 0.0f);
}

// ---------------------------------------------------------------------------
__global__ __launch_bounds__(256)
void colmean_part_k(const float* x, double* part) {
  int col = blockIdx.x * 256 + threadIdx.x;
  int rs = blockIdx.y;
  double acc = 0.0;
  for (int r = rs * 512; r < (rs + 1) * 512; ++r)
    acc += (double)x[(size_t)r * D_N + col];
  part[(size_t)rs * D_N + col] = acc;
}

__global__ __launch_bounds__(256)
void colmean_comb_k(const double* part, float* m) {
  int col = blockIdx.x * 256 + threadIdx.x;
  double acc = 0.0;
  for (int rs = 0; rs < 16; ++rs) acc += part[(size_t)rs * D_N + col];
  m[col] = (float)(acc / (double)B_N);
}

__global__ void inits_k(float* S, int n, unsigned seed) {
  int i = blockIdx.x * 256 + threadIdx.x;
  if (i < n) S[i] = hashf((unsigned)i * 2654435761u + seed);
}

// ---------------------------------------------------------------------------
// Blocked LDL^T (NB=16, register panel via __shfl in wave 0; GEMM-style
// rank-16 trailing update). 512 threads. (validated v7-v9)
// ---------------------------------------------------------------------------
__device__ __forceinline__
void ldl128(float (&A)[128][129], float* Dsh, int tid) {
  for (int b = 0; b < 8; ++b) {
    const int o = b * 16;
    if (tid < 64) {
      const int lane = tid;
      float ra[16], rb[16], Dv[16];
#pragma unroll
      for (int q = 0; q < 16; ++q) {
        ra[q] = A[lane][o + q];
        rb[q] = A[lane + 64][o + q];
      }
#pragma unroll
      for (int jj = 0; jj < 16; ++jj) {
        const int c = o + jj;
        float pj = (c < 64) ? __shfl(ra[jj], c) : __shfl(rb[jj], c - 64);
        pj = fmaxf(pj, 1e-30f);
        Dv[jj] = pj;
        const float rdj = 1.0f / pj;
        const float ua = ra[jj] * rdj;
        const float ub = rb[jj] * rdj;
#pragma unroll
        for (int t = jj + 1; t < 16; ++t) {
          const int rt = o + t;
          float atj = (rt < 64) ? __shfl(ra[jj], rt) : __shfl(rb[jj], rt - 64);
          ra[t] -= ua * atj;
          rb[t] -= ub * atj;
        }
        ra[jj] = ua; rb[jj] = ub;
      }
#pragma unroll
      for (int q = 0; q < 16; ++q) {
        A[lane][o + q] = ra[q];
        A[lane + 64][o + q] = rb[q];
      }
#pragma unroll
      for (int q = 0; q < 16; ++q)
        if (lane == q) Dsh[o + q] = Dv[q];
    }
    __syncthreads();
    if (o + 16 < 128) {
      const int tx = tid & 15, ty = tid >> 4;
      for (int i = o + 16 + ty; i < 128; i += 32) {
        float w[16];
#pragma unroll
        for (int q = 0; q < 16; ++q) w[q] = A[i][o + q] * Dsh[o + q];
        for (int t = o + 16 + tx; t <= i; t += 16) {
          float s = A[i][t];
#pragma unroll
          for (int q = 0; q < 16; ++q) s -= w[q] * A[t][o + q];
          A[i][t] = s;
        }
      }
    }
    __syncthreads();
  }
}

// chol + BLOCKED-RECURSIVE triangular inverse. W = raw scratch >= 1904 floats.
// Output: Bm[c][i] = Linv[i][c] (i>=c), upper zero. 512 threads.
// Diagonal 16x16 blocks: direct per-column solve (chain <= 120).
// Off-diag blocks, levels d=1..7 (independent within level):
//   Wk_IJ[r][c] = sum_{u=16J}^{16I-1} L[16I+r][u] * Bm[16J+c][u]
//   Linv_IJ[r][c] = -sum_{t<=r} V_II[r][t]*Wk[t][c],  V_II[r][t]=Bm[16I+t][16I+r]
__device__ __forceinline__
void cholinv128(float (&A)[128][129], float (&Bm)[128][129],
                float* W, float* Dsh, float* sqv, int tid) {
  for (int idx = tid; idx < 128 * 129; idx += 512)
    (&Bm[0][0])[idx] = 0.0f;
  __syncthreads();
  ldl128(A, Dsh, tid);
  if (tid < 128) sqv[tid] = sqrtf(Dsh[tid]);
  __syncthreads();
  for (int idx = tid; idx < 128 * 128; idx += 512) {
    int i = idx >> 7, j = idx & 127;
    if (j <= i) A[i][j] *= sqv[j];
  }
  __syncthreads();
  // diagonal block inversions
  if (tid < 128) {
    const int o = (tid >> 4) * 16, c = tid & 15;
    for (int i = c; i < 16; ++i) {
      float s = (i == c) ? 1.0f : 0.0f;
      for (int t = c; t < i; ++t) s -= A[o + i][o + t] * Bm[o + c][o + t];
      Bm[o + c][o + i] = s / A[o + i][o + i];
    }
  }
  __syncthreads();
  // off-diagonal levels
  for (int d = 1; d <= 7; ++d) {
    const int np = 8 - d;
    for (int q = tid; q < np * 256; q += 512) {
      int p = q >> 8, rc = q & 255;
      int r = rc >> 4, c = rc & 15;
      int I = p + d;
      float s = 0.0f;
      for (int u = 16 * p; u < 16 * I; ++u)
        s += A[16 * I + r][u] * Bm[16 * p + c][u];
      W[p * 272 + r * 17 + c] = s;
    }
    __syncthreads();
    for (int q = tid; q < np * 256; q += 512) {
      int p = q >> 8, rc = q & 255;
      int r = rc >> 4, c = rc & 15;
      int I = p + d;
      float s = 0.0f;
      for (int t = 0; t <= r; ++t)
        s -= Bm[16 * I + t][16 * I + r] * W[p * 272 + t * 17 + c];
      Bm[16 * p + c][16 * I + r] = s;
    }
    __syncthreads();
  }
}

// ---------------------------------------------------------------------------
__global__ __launch_bounds__(512)
void chol128_k(const float* Gin, int ldg, float* LinvT, double* logdet, float* Sinv) {
  __shared__ float A[128][129];
  __shared__ float Bm[128][129];
  __shared__ float Y[2048];
  __shared__ float Dsh[128], sqv[128];
  const int tid = threadIdx.x;
  for (int idx = tid; idx < 128 * 128; idx += 512)
    A[idx >> 7][idx & 127] = Gin[(size_t)(idx >> 7) * ldg + (idx & 127)];
  __syncthreads();
  cholinv128(A, Bm, Y, Dsh, sqv, tid);
  if (logdet && tid == 0) {
    double s = 0.0;
    for (int j = 0; j < 128; ++j) s += log((double)Dsh[j]);
    *logdet = s;
  }
  if (LinvT)
    for (int idx = tid; idx < 128 * 128; idx += 512)
      LinvT[idx] = Bm[idx >> 7][idx & 127];
  if (Sinv)
    for (int idx = tid; idx < 128 * 128; idx += 512) {
      int i = idx >> 7, j = idx & 127;
      int t0 = (i > j) ? i : j;
      float s = 0.0f;
      for (int t = t0; t < 128; ++t) s += Bm[i][t] * Bm[j][t];
      Sinv[idx] = s;
    }
}

// ---------------------------------------------------------------------------
// qrf_k: fused blocked CholQR-256 (validated v9 structure, new cholinv).
//   Rinv = [[L11^-T, -L11^-T L21^T L22^-T], [0, L22^-T]]
// ---------------------------------------------------------------------------
__global__ __launch_bounds__(512)
void qrf_k(const float* G, int ldg, float* Rinv, float* Pg) {
  __shared__ float A[128][129];
  __shared__ float Bm[128][129];
  __shared__ float SY[4224];
  __shared__ float Dsh[128], sqv[128];
  const int tid = threadIdx.x;
  const int jl = tid & 31;        // col j(c) = jl + 32c, c<4
  const int il = tid >> 5;        // row i(r) = il + 16r, r<8
  // phase 1: chol+inv of G11 -> Bm = Li11T
  for (int idx = tid; idx < 128 * 128; idx += 512)
    A[idx >> 7][idx & 127] = G[(size_t)(idx >> 7) * ldg + (idx & 127)];
  __syncthreads();
  cholinv128(A, Bm, SY, Dsh, sqv, tid);
  for (int idx = tid; idx < 128 * 128; idx += 512) {
    int k = idx >> 7, j = idx & 127;
    Rinv[(size_t)k * 256 + j] = Bm[k][j];
    Rinv[(size_t)(128 + k) * 256 + j] = 0.0f;
  }
  __syncthreads();
  // phase 2: L21[i][j] = sum_t G21[i][t] * Bm[t][j]   (G21 staged in SY)
  {
    float acc[8][4] = {};
    for (int t0 = 0; t0 < 128; t0 += 32) {
      for (int q = tid; q < 128 * 8; q += 512) {
        int i = q >> 3, c4 = q & 7;
        *(float4*)&SY[i * 33 + c4 * 4] =
            *(const float4*)&G[(size_t)(128 + i) * ldg + t0 + c4 * 4];
      }
      __syncthreads();
      for (int t = 0; t < 32; ++t) {
        float bv[4];
#pragma unroll
        for (int c = 0; c < 4; ++c) bv[c] = Bm[t0 + t][jl + 32 * c];
#pragma unroll
        for (int r = 0; r < 8; ++r) {
          float gv = SY[(il + 16 * r) * 33 + t];
#pragma unroll
          for (int c = 0; c < 4; ++c) acc[r][c] += gv * bv[c];
        }
      }
      __syncthreads();
    }
#pragma unroll
    for (int r = 0; r < 8; ++r)
#pragma unroll
      for (int c = 0; c < 4; ++c) {
        int i = il + 16 * r, j = jl + 32 * c;
        A[i][j] = acc[r][c];
        Pg[(size_t)i * 128 + j] = acc[r][c];
      }
  }
  __syncthreads();
  // phase 3: Schur = G22 - L21 L21^T  (A holds L21; write into A)
  {
    float acc[8][4] = {};
    for (int t = 0; t < 128; ++t) {
      float bv[4];
#pragma unroll
      for (int c = 0; c < 4; ++c) bv[c] = A[jl + 32 * c][t];
#pragma unroll
      for (int r = 0; r < 8; ++r) {
        float av = A[il + 16 * r][t];
#pragma unroll
        for (int c = 0; c < 4; ++c) acc[r][c] += av * bv[c];
      }
    }
    __syncthreads();
#pragma unroll
    for (int r = 0; r < 8; ++r)
#pragma unroll
      for (int c = 0; c < 4; ++c) {
        int i = il + 16 * r, j = jl + 32 * c;
        A[i][j] = G[(size_t)(128 + i) * ldg + 128 + j] - acc[r][c];
      }
  }
  __syncthreads();
  // phase 4: chol+inv of Schur -> Bm = Li22T; Rinv BR
  cholinv128(A, Bm, SY, Dsh, sqv, tid);
  for (int idx = tid; idx < 128 * 128; idx += 512) {
    int k = idx >> 7, j = idx & 127;
    Rinv[(size_t)(128 + k) * 256 + 128 + j] = Bm[k][j];
  }
  __syncthreads();
  // phase 5: M1[t][j] = sum_s Pg[s][t] * Bm[s][j]   (Pg staged) -> A
  {
    float acc[8][4] = {};
    for (int s0 = 0; s0 < 128; s0 += 32) {
      for (int q = tid; q < 32 * 32; q += 512) {
        int sr = q >> 5, c4 = q & 31;
        *(float4*)&SY[sr * 132 + c4 * 4] =
            *(const float4*)&Pg[(size_t)(s0 + sr) * 128 + c4 * 4];
      }
      __syncthreads();
      for (int s = 0; s < 32; ++s) {
        float bv[4];
#pragma unroll
        for (int c = 0; c < 4; ++c) bv[c] = Bm[s0 + s][jl + 32 * c];
#pragma unroll
        for (int r = 0; r < 8; ++r) {
          float pv = SY[s * 132 + il + 16 * r];
#pragma unroll
          for (int c = 0; c < 4; ++c) acc[r][c] += pv * bv[c];
        }
      }
      __syncthreads();
    }
#pragma unroll
    for (int r = 0; r < 8; ++r)
#pragma unroll
      for (int c = 0; c < 4; ++c)
        A[il + 16 * r][jl + 32 * c] = acc[r][c];
  }
  __syncthreads();
  // phase 6: TR[k][j] = -sum_t RinvTL[k][t] * M1[t][j]  (RinvTL staged)
  {
    float acc[8][4] = {};
    for (int t0 = 0; t0 < 128; t0 += 32) {
      for (int q = tid; q < 128 * 8; q += 512) {
        int k = q >> 3, c4 = q & 7;
        *(float4*)&SY[k * 33 + c4 * 4] =
            *(const float4*)&Rinv[(size_t)k * 256 + t0 + c4 * 4];
      }
      __syncthreads();
      for (int t = 0; t < 32; ++t) {
        float bv[4];
#pragma unroll
        for (int c = 0; c < 4; ++c) bv[c] = A[t0 + t][jl + 32 * c];
#pragma unroll
        for (int r = 0; r < 8; ++r) {
          float rv = SY[(il + 16 * r) * 33 + t];
#pragma unroll
          for (int c = 0; c < 4; ++c) acc[r][c] += rv * bv[c];
        }
      }
      __syncthreads();
    }
#pragma unroll
    for (int r = 0; r < 8; ++r)
#pragma unroll
      for (int c = 0; c < 4; ++c)
        Rinv[(size_t)(il + 16 * r) * 256 + 128 + jl + 32 * c] = -acc[r][c];
  }
}

__global__ __launch_bounds__(128)
void mw_k(const float* m, const float* W, float* mW) {
  int j = threadIdx.x;
  double acc = 0.0;
  for (int c = 0; c < D_N; ++c) acc += (double)m[c] * (double)W[(size_t)c * K_N + j];
  mW[j] = (float)acc;
}

// ---------------------------------------------------------------------------
__global__ __launch_bounds__(256)
void count_sort_k(const int* lab, int* perm, int* counts, int* offs) {
  __shared__ int cnt[NLAB][256];
  __shared__ int labOff[NLAB + 1];
  const int tid = threadIdx.x;
  int lc[NLAB];
#pragma unroll
  for (int l = 0; l < NLAB; ++l) lc[l] = 0;
  for (int r = tid * 32; r < tid * 32 + 32; ++r) {
    int l = lab[r]; l = (l < 0) ? 0 : (l > 9 ? 9 : l);
    lc[l]++;
  }
#pragma unroll
  for (int l = 0; l < NLAB; ++l) cnt[l][tid] = lc[l];
  __syncthreads();
  if (tid < NLAB) {
    int run = 0;
    for (int i = 0; i < 256; ++i) { int v = cnt[tid][i]; cnt[tid][i] = run; run += v; }
    counts[tid] = run;
  }
  __syncthreads();
  if (tid == 0) {
    int run = 0;
    for (int l = 0; l < NLAB; ++l) { labOff[l] = run; run += counts[l]; }
    labOff[NLAB] = run;
    for (int l = 0; l <= NLAB; ++l) offs[l] = labOff[l];
  }
  __syncthreads();
  int lc2[NLAB];
#pragma unroll
  for (int l = 0; l < NLAB; ++l) lc2[l] = 0;
  for (int r = tid * 32; r < tid * 32 + 32; ++r) {
    int l = lab[r]; l = (l < 0) ? 0 : (l > 9 ? 9 : l);
    int pos = labOff[l] + cnt[l][tid] + lc2[l];
    lc2[l]++;
    perm[pos] = r;
  }
}

__global__ __launch_bounds__(256)
void gather_k(const float* z, const int* perm, float* zs) {
  int g = blockIdx.x * 256 + threadIdx.x;
  int row = g >> 5, q = g & 31;
  const float4* zf = (const float4*)z;
  float4* of = (float4*)zs;
  of[(size_t)row * 32 + q] = zf[(size_t)perm[row] * 32 + q];
}

__global__ __launch_bounds__(128)
void labstat_part_k(const float* zs, const int* offs, double* part) {
  int l = blockIdx.x >> 3, s = blockIdx.x & 7;
  int j = threadIdx.x;
  int r0, r1;
  if (l < NLAB) {
    int st = offs[l], en = offs[l + 1], len = en - st;
    r0 = st + (int)(((long long)len * s) >> 3);
    r1 = st + (int)(((long long)len * (s + 1)) >> 3);
  } else {
    r0 = s * 1024; r1 = r0 + 1024;
  }
  double acc = 0.0;
  for (int r = r0; r < r1; ++r) acc += (double)zs[(size_t)r * K_N + j];
  part[((size_t)l * 8 + s) * K_N + j] = acc;
}

__global__ __launch_bounds__(128)
void labstat_comb_k(const double* part, float* sum_mu, float* muT) {
  int j = threadIdx.x;
  for (int l = 0; l < NLAB; ++l) {
    double a = 0.0;
    for (int s = 0; s < 8; ++s) a += part[((size_t)l * 8 + s) * K_N + j];
    sum_mu[l * K_N + j] = (float)a;
  }
  double t = 0.0;
  for (int s = 0; s < 8; ++s) t += part[((size_t)NLAB * 8 + s) * K_N + j];
  muT[j] = (float)(t / (double)B_N);
}

__global__ __launch_bounds__(256)
void sigsum_k(const float* zs, const int* offs, const float* muT, float* SigS) {
  int l = blockIdx.x >> 2, t = blockIdx.x & 3;
  int i0 = (t >> 1) * 64, j0 = (t & 1) * 64;
  __shared__ float Zi[32][66], Zj[32][66];
  __shared__ float muL[128];
  int tid = threadIdx.x, tx = tid & 15, ty = tid >> 4;
  if (tid < 128) muL[tid] = muT[tid];
  __syncthreads();
  int start = offs[l], end = offs[l + 1];
  float acc[4][4] = {};
  for (int base = start; base < end; base += 32) {
#pragma unroll
    for (int p = 0; p < 8; ++p) {
      int idx = tid + p * 256;
      int rr = idx >> 6, cc = idx & 63;
      int r = base + rr;
      float vi = 0.0f, vj = 0.0f;
      if (r < end) {
        vi = zs[(size_t)r * K_N + i0 + cc] - muL[i0 + cc];
        vj = zs[(size_t)r * K_N + j0 + cc] - muL[j0 + cc];
      }
      Zi[rr][cc] = vi; Zj[rr][cc] = vj;
    }
    __syncthreads();
    for (int rr = 0; rr < 32; ++rr) {
      float ra[4], rb[4];
#pragma unroll
      for (int r = 0; r < 4; ++r) ra[r] = Zi[rr][ty * 4 + r];
#pragma unroll
      for (int c = 0; c < 4; ++c) rb[c] = Zj[rr][tx * 4 + c];
#pragma unroll
      for (int r = 0; r < 4; ++r)
#pragma unroll
        for (int c = 0; c < 4; ++c) acc[r][c] += ra[r] * rb[c];
    }
    __syncthreads();
  }
#pragma unroll
  for (int r = 0; r < 4; ++r)
#pragma unroll
    for (int c = 0; c < 4; ++c)
      SigS[((size_t)l * K_N + i0 + ty * 4 + r) * K_N + j0 + tx * 4 + c] = acc[r][c];
}

__global__ __launch_bounds__(256)
void sigt_comb_k(const float* SigS, float* SigT) {
  int idx = blockIdx.x * 256 + threadIdx.x;
  int i = idx >> 7, j = idx & 127;
  double s = 0.0;
  for (int l = 0; l < NLAB; ++l) s += (double)SigS[(size_t)l * 16384 + idx];
  SigT[idx] = (float)(s / (double)B_N) + ((i == j) ? 1.0f : 0.0f);
}

// ---------------------------------------------------------------------------
__global__ __launch_bounds__(512)
void perlabel_k(const float* SigS, const float* Sinv, const float* mu,
                const float* sum_mu, const int* counts, const double* logdet_t,
                double* klout, int* present) {
  int l = blockIdx.x, tid = threadIdx.x;
  __shared__ float Amat[128][129];
  __shared__ double red[512];
  __shared__ float dv[128];
  __shared__ float Dsh[128];
  int cnt = counts[l];
  float sc = (cnt > 0) ? (float)cnt : 1.0f;
  for (int idx = tid; idx < 128 * 128; idx += 512) {
    int i = idx >> 7, j = idx & 127;
    Amat[i][j] = SigS[((size_t)l * K_N + i) * K_N + j] / sc + ((i == j) ? 1.0f : 0.0f);
  }
  if (tid < 128) dv[tid] = mu[tid] - sum_mu[l * K_N + tid] / sc;
  __syncthreads();
  double tr = 0.0, mh = 0.0;
  for (int idx = tid; idx < 128 * 128; idx += 512) {
    int i = idx >> 7, j = idx & 127;
    double sv = (double)Sinv[idx];
    tr += sv * (double)Amat[i][j];
    mh += sv * (double)dv[i] * (double)dv[j];
  }
  red[tid] = tr; __syncthreads();
  for (int off = 256; off > 0; off >>= 1) { if (tid < off) red[tid] += red[tid + off]; __syncthreads(); }
  double trv = red[0]; __syncthreads();
  red[tid] = mh; __syncthreads();
  for (int off = 256; off > 0; off >>= 1) { if (tid < off) red[tid] += red[tid + off]; __syncthreads(); }
  double mhv = red[0]; __syncthreads();
  ldl128(Amat, Dsh, tid);
  if (tid == 0) {
    double ld = 0.0;
    for (int j = 0; j < 128; ++j) ld += log((double)Dsh[j]);
    klout[l] = 0.5 * (trv + mhv - 128.0 + logdet_t[0] - ld);
    present[l] = (cnt > 0) ? 1 : 0;
  }
}

__global__ void finalize_k(const double* kl, const int* present, float* out) {
  if (threadIdx.x == 0 && blockIdx.x == 0) {
    double s = 0.0; int np = 0;
    for (int l = 0; l < NLAB; ++l)
      if (present[l]) { s += kl[l]; np++; }
    out[0] = (float)((np > 0) ? s / ((double)np * (double)B_N) : 0.0);
  }
}

// ===========================================================================
// Host side
// ===========================================================================
static inline GArgs mkg(const float* A, int lda, const float* B, int ldb,
                        float* C, int ldc, int K, float alpha) {
  GArgs g{};
  g.A = A; g.B = B; g.C = C; g.lda = lda; g.ldb = ldb; g.ldc = ldc;
  g.K = K; g.alpha = alpha;
  return g;
}

static inline void run_g(hipStream_t st, bool akm, bool bt, GArgs g,
                         int M, int N, int ks, float* Ppart) {
  if (ks > 1) {
    g.Cp = Ppart; g.mn = (size_t)M * N; g.pn = N;
    dim3 grid(M / 64, N / 64, ks);
    if (akm)     hipLaunchKernelGGL((gemm_k<true, false>),  grid, dim3(256), 0, st, g);
    else if (bt) hipLaunchKernelGGL((gemm_k<false, true>),  grid, dim3(256), 0, st, g);
    else         hipLaunchKernelGGL((gemm_k<false, false>), grid, dim3(256), 0, st, g);
    CArgs c{Ppart, g.C, (size_t)M * N, N, g.ldc, ks,
            g.C1, g.b1, g.ldc1, g.C2, g.b2, g.ldc2,
            g.r1u, g.r1v, g.r1c, g.radd, g.raddc, g.addI,
            g.out2, g.sc2, g.dg2};
    hipLaunchKernelGGL(combine_k, dim3((unsigned)(((size_t)M * N + 255) / 256)),
                       dim3(256), 0, st, c);
  } else {
    dim3 grid(M / 64, N / 64);
    if (akm)     hipLaunchKernelGGL((gemm_k<true, false>),  grid, dim3(256), 0, st, g);
    else if (bt) hipLaunchKernelGGL((gemm_k<false, true>),  grid, dim3(256), 0, st, g);
    else         hipLaunchKernelGGL((gemm_k<false, false>), grid, dim3(256), 0, st, g);
  }
}

// 1024x1024 AKM product via 128-tile partial kernel + combine epilogue.
static inline void run_big(hipStream_t st, GArgs g, int ks, float* Ppart) {
  if (ks > 1) {
    dim3 grid(8, 8, ks);
    hipLaunchKernelGGL(gemm128p_k, grid, dim3(256), 0, st,
                       g.A, g.B, g.lda, g.ldb, g.K, g.alpha, Ppart, D_N,
                       (size_t)D_N * D_N);
    CArgs c{Ppart, g.C, (size_t)D_N * D_N, D_N, g.ldc, ks,
            g.C1, g.b1, g.ldc1, g.C2, g.b2, g.ldc2,
            g.r1u, g.r1v, g.r1c, g.radd, g.raddc, g.addI,
            g.out2, g.sc2, g.dg2};
    hipLaunchKernelGGL(combine_k, dim3((unsigned)(((size_t)D_N * D_N + 255) / 256)),
                       dim3(256), 0, st, c);
  } else {
    run_g(st, true, false, g, D_N, D_N, 1, nullptr);
  }
}

extern "C" void kernel_launch(void* const* d_in, const int* in_sizes, int n_in,
                              void* d_out, int out_size, void* d_ws, size_t ws_size,
                              hipStream_t stream) {
  const float* x = (const float*)d_in[0];
  const int* lab = (const int*)d_in[1];
  float* out = (float*)d_out;

  size_t off = 0;
  auto alloc = [&](size_t nbytes) -> void* {
    void* r = (void*)((char*)d_ws + off);
    off += ((nbytes + 255) / 256) * 256;
    return r;
  };
  float*  m     = (float*) alloc(D_N * 4);
  float*  Cn    = (float*) alloc((size_t)D_N * D_N * 4);
  float*  At    = (float*) alloc((size_t)D_N * D_N * 4);  // Atilde -> T4 -> zs
  float*  T2    = (float*) alloc((size_t)D_N * D_N * 4);  // T2 -> z
  float*  Fo    = (float*) alloc((size_t)D_N * D_N * 4);  // outer filter T6
  float*  SA    = (float*) alloc((size_t)D_N * M_N * 4);
  float*  SB    = (float*) alloc((size_t)D_N * M_N * 4);
  float*  SC    = (float*) alloc((size_t)D_N * M_N * 4);
  float*  G256  = (float*) alloc((size_t)M_N * M_N * 4);  // -> F12i
  float*  Tm    = (float*) alloc((size_t)M_N * M_N * 4);
  float*  Rb    = (float*) alloc((size_t)M_N * M_N * 4);  // Rinv from qrf
  float*  Pg2   = (float*) alloc((size_t)K_N * K_N * 4);  // qrf scratch (L21)
  float*  Tt    = (float*) alloc((size_t)M_N * M_N * 4);
  float*  T2i   = (float*) alloc((size_t)M_N * M_N * 4);
  float*  T4i   = (float*) alloc((size_t)M_N * M_N * 4);
  float*  F6i   = (float*) alloc((size_t)M_N * M_N * 4);
  float*  VA    = (float*) alloc((size_t)M_N * K_N * 4);
  float*  VB    = (float*) alloc((size_t)M_N * K_N * 4);
  float*  G128  = (float*) alloc((size_t)K_N * K_N * 4);
  float*  Li128 = (float*) alloc((size_t)K_N * K_N * 4);
  float*  Wa    = (float*) alloc((size_t)D_N * K_N * 4);
  float*  Wb    = (float*) alloc((size_t)D_N * K_N * 4);
  float*  mW    = (float*) alloc(K_N * 4);
  double* partM = (double*)alloc((size_t)16 * D_N * 8);
  double* partL = (double*)alloc((size_t)11 * 8 * K_N * 8);
  float*  sumMu = (float*) alloc(NLAB * K_N * 4);
  float*  muT   = (float*) alloc(K_N * 4);
  float*  SigT  = (float*) alloc((size_t)K_N * K_N * 4);
  float*  Sinv  = (float*) alloc((size_t)K_N * K_N * 4);
  float*  SigS  = (float*) alloc((size_t)NLAB * K_N * K_N * 4);
  double* logdet_t = (double*)alloc(16);
  double* klv      = (double*)alloc(NLAB * 8);
  int*    counts = (int*)alloc(16 * 4);
  int*    offs   = (int*)alloc(16 * 4);
  int*    present= (int*)alloc(16 * 4);
  int*    perm   = (int*)alloc(B_N * 4);
  float*  T4   = At;    // alias: At dead once T2 exists
  float*  F12i = G256;  // alias: G256 dead after outer segs
  float*  zs   = At;    // alias: T4 dead after Fo; zs written step 9
  float*  z    = T2;    // alias: T2 dead after Fo
  size_t rem = (ws_size > off) ? (ws_size - off) : 0;
  int KS = 1, KSC = 1;
  size_t pbytes = 0;
  if (rem >= (size_t)33 * 1024 * 1024)      { KSC = 8; KS = 8; pbytes = (size_t)32 * 1024 * 1024; }
  else if (rem >= (size_t)17 * 1024 * 1024) { KSC = 4; KS = 4; pbytes = (size_t)16 * 1024 * 1024; }
  else if (rem >= (size_t)9 * 1024 * 1024)  { KSC = 2; KS = 2; pbytes = (size_t)8 * 1024 * 1024; }
  float* Ppart = pbytes ? (float*)alloc(pbytes) : nullptr;
  const int gks = KS;   // split factor for small-output Grams (K>=256)
  (void)in_sizes; (void)n_in; (void)out_size;

  // 1) column means; Cn = x^T x / B - m m^T ; At = 1.6*Cn - I (fused)
  hipLaunchKernelGGL(colmean_part_k, dim3(4, 16), dim3(256), 0, stream, x, partM);
  hipLaunchKernelGGL(colmean_comb_k, dim3(4), dim3(256), 0, stream, partM, m);
  {
    GArgs g = mkg(x, D_N, x, D_N, Cn, D_N, B_N, 1.0f / (float)B_N);
    g.r1u = m; g.r1v = m; g.r1c = -1.0f;
    if (KSC > 1) { g.out2 = At; g.sc2 = 1.6f; g.dg2 = -1.0f; }
    run_big(stream, g, KSC, Ppart);
    if (KSC == 1)
      hipLaunchKernelGGL(scaleshift_k, dim3((D_N * D_N + 255) / 256), dim3(256),
                         0, stream, Cn, At, D_N, 1.6f, -1.0f);
  }

  // 2) Outer filter Fo = T6(At) = 2*T2*T4 - T2, band [0,1.25] (c=d=0.625)
  {
    GArgs g = mkg(At, D_N, At, D_N, T2, D_N, D_N, 2.0f);  // T2 = 2 At^2 - I
    g.addI = -1.0f;
    run_big(stream, g, KSC, Ppart);
    g = mkg(T2, D_N, T2, D_N, T4, D_N, D_N, 2.0f);        // T4 = 2 T2^2 - I
    g.addI = -1.0f;
    run_big(stream, g, KSC, Ppart);
    g = mkg(T2, D_N, T4, D_N, Fo, D_N, D_N, 2.0f);        // T6 = 2 T2 T4 - T2
    g.C1 = T2; g.b1 = -1.0f; g.ldc1 = D_N;
    run_big(stream, g, KSC, Ppart);
  }

  // Fused blocked CholQR-256: Gram -> qrf (Rinv) -> Snew = S * Rinv
  auto qr256 = [&](float* S, float* Snew) {
    GArgs g = mkg(S, M_N, S, M_N, G256, M_N, D_N, 1.0f);
    run_g(stream, true, false, g, M_N, M_N, gks, Ppart);
    hipLaunchKernelGGL(qrf_k, dim3(1), dim3(512), 0, stream, G256, M_N, Rb, Pg2);
    g = mkg(S, M_N, Rb, M_N, Snew, M_N, M_N, 1.0f);
    run_g(stream, false, false, g, D_N, M_N, KS, Ppart);
  };

  // 3) Outer: 2 segments of {S <- Fo @ S ; CholQR-256}
  hipLaunchKernelGGL(inits_k, dim3((D_N * M_N + 255) / 256), dim3(256), 0, stream,
                     SA, D_N * M_N, 12345u);
  float* Scur = SA; float* t1 = SB; float* t2 = SC;
  for (int seg = 0; seg < 2; ++seg) {
    GArgs g = mkg(Fo, D_N, Scur, M_N, t1, M_N, D_N, 1.0f);
    run_g(stream, true, false, g, D_N, M_N, KS, Ppart);
    qr256(t1, t2);
    float* t = Scur; Scur = t2; t2 = t;
  }

  // 4) T = S^T (Cn S)
  {
    GArgs g = mkg(Cn, D_N, Scur, M_N, t1, M_N, D_N, 1.0f);
    run_g(stream, true, false, g, D_N, M_N, KS, Ppart);
    g = mkg(Scur, M_N, t1, M_N, Tm, M_N, D_N, 1.0f);
    run_g(stream, true, false, g, M_N, M_N, gks, Ppart);
  }

  // 5) Inner filter F12 = T12(Tt) = 2*T6(Tt)^2 - I, band [0,1.27] (c=d=0.635)
  hipLaunchKernelGGL(symscale_k, dim3((M_N * M_N + 255) / 256), dim3(256), 0,
                     stream, Tm, Tt, M_N, 1.0f / 0.635f, -1.0f);
  {
    GArgs g = mkg(Tt, M_N, Tt, M_N, T2i, M_N, M_N, 2.0f);
    g.addI = -1.0f;
    run_g(stream, true, false, g, M_N, M_N, 1, nullptr);
    g = mkg(T2i, M_N, T2i, M_N, T4i, M_N, M_N, 2.0f);
    g.addI = -1.0f;
    run_g(stream, true, false, g, M_N, M_N, 1, nullptr);
    g = mkg(T2i, M_N, T4i, M_N, F6i, M_N, M_N, 2.0f);
    g.C1 = T2i; g.b1 = -1.0f; g.ldc1 = M_N;
    run_g(stream, true, false, g, M_N, M_N, 1, nullptr);
    g = mkg(F6i, M_N, F6i, M_N, F12i, M_N, M_N, 2.0f);
    g.addI = -1.0f;
    run_g(stream, true, false, g, M_N, M_N, 1, nullptr);
  }

  // 6) Inner: 1 segment {V <- F12 @ V ; CholQR-128}
  hipLaunchKernelGGL(inits_k, dim3((M_N * K_N + 255) / 256), dim3(256), 0, stream,
                     VA, M_N * K_N, 777u);
  {
    GArgs g = mkg(F12i, M_N, VA, K_N, VB, K_N, M_N, 1.0f);
    run_g(stream, true, false, g, M_N, K_N, 1, nullptr);
    g = mkg(VB, K_N, VB, K_N, G128, K_N, M_N, 1.0f);
    run_g(stream, true, false, g, K_N, K_N, 1, nullptr);
    hipLaunchKernelGGL(chol128_k, dim3(1), dim3(512), 0, stream,
                       G128, K_N, Li128, (double*)nullptr, (float*)nullptr);
    g = mkg(VB, K_N, Li128, K_N, VA, K_N, K_N, 1.0f);
    run_g(stream, false, false, g, M_N, K_N, 1, nullptr);
  }

  // 7) W = S*V, exact CholQR-128 on W (CholQR2 pattern)
  {
    GArgs g = mkg(Scur, M_N, VA, K_N, Wa, K_N, M_N, 1.0f);
    run_g(stream, false, false, g, D_N, K_N, 1, nullptr);
    g = mkg(Wa, K_N, Wa, K_N, G128, K_N, D_N, 1.0f);
    run_g(stream, true, false, g, K_N, K_N, gks, Ppart);
    hipLaunchKernelGGL(chol128_k, dim3(1), dim3(512), 0, stream,
                       G128, K_N, Li128, (double*)nullptr, (float*)nullptr);
    g = mkg(Wa, K_N, Li128, K_N, Wb, K_N, K_N, 1.0f);
    run_g(stream, false, false, g, D_N, K_N, 1, nullptr);
  }

  // 8) z = x W - 1 (m^T W)
  hipLaunchKernelGGL(mw_k, dim3(1), dim3(128), 0, stream, m, Wb, mW);
  {
    GArgs g = mkg(x, D_N, Wb, K_N, z, K_N, D_N, 1.0f);
    g.radd = mW; g.raddc = -1.0f;
    run_g(stream, false, false, g, B_N, K_N, KS, Ppart);
  }

  // 9) sort rows by label; gather into zs
  hipLaunchKernelGGL(count_sort_k, dim3(1), dim3(256), 0, stream,
                     lab, perm, counts, offs);
  hipLaunchKernelGGL(gather_k, dim3(B_N * 32 / 256), dim3(256), 0, stream,
                     z, perm, zs);

  // 10) label and global column sums
  hipLaunchKernelGGL(labstat_part_k, dim3(11 * 8), dim3(128), 0, stream,
                     zs, offs, partL);
  hipLaunchKernelGGL(labstat_comb_k, dim3(1), dim3(128), 0, stream,
                     partL, sumMu, muT);

  // 11) per-label Sigma sums; SigT; Sinv + logdet
  hipLaunchKernelGGL(sigsum_k, dim3(NLAB * 4), dim3(256), 0, stream,
                     zs, offs, muT, SigS);
  hipLaunchKernelGGL(sigt_comb_k, dim3(64), dim3(256), 0, stream, SigS, SigT);
  hipLaunchKernelGGL(chol128_k, dim3(1), dim3(512), 0, stream,
                     SigT, K_N, (float*)nullptr, logdet_t, Sinv);

  // 12) per-label KL, reduce
  hipLaunchKernelGGL(perlabel_k, dim3(NLAB), dim3(512), 0, stream,
                     SigS, Sinv, muT, sumMu, counts, logdet_t, klv, present);
  hipLaunchKernelGGL(finalize_k, dim3(1), dim3(64), 0, stream, klv, present, out);
}